// Round 2
// baseline (372.453 us; speedup 1.0000x reference)
//
#include <hip/hip_runtime.h>
#include <stdint.h>

typedef __attribute__((ext_vector_type(8))) __bf16 bf16x8;
typedef __attribute__((ext_vector_type(4))) float f32x4;

#define N_LEAVES 524288

// fp32 -> bf16 round-to-nearest-even (bit manip; values are finite)
__device__ __forceinline__ uint16_t f2bf(float f) {
  uint32_t u = __float_as_uint(f);
  return (uint16_t)((u + 0x7fffu + ((u >> 16) & 1u)) >> 16);
}

// Swizzled LDS byte address for A-tile: row-major [rows][256] bf16 (512 B/row),
// 16B chunks XORed by (row&7) to kill the 512B-stride bank conflict (T2).
__device__ __forceinline__ int lds_addr(int row, int chunk) {
  return row * 512 + ((chunk ^ (row & 7)) << 4);
}

// ---- shared MFMA compute + epilogue for one 64-row x 128-col tile ----
// A staged (swizzled) in Alds. B (Wc_w as bf16, row-major [128][256]) in regs.
// Y written bf16 row-major [n][128].
__device__ __forceinline__ void mfma_tile(
    const uint8_t* Alds, const uint16_t* __restrict__ Wbf,
    const float* __restrict__ Wnon, const float* __restrict__ bias,
    const int* __restrict__ nidx, int lvl_off, int r0,
    uint16_t* __restrict__ Y)
{
  const int tid = threadIdx.x;
  const int w = tid >> 6, lane = tid & 63;
  const int Rw = (w >> 2) * 32;      // 2 wave-rows of 32
  const int Cw = (w & 3) * 32;       // 4 wave-cols of 32
  const int l15 = lane & 15, l4 = lane >> 4;

  // B fragments: lane holds col (Cw+cf*16+l15), k = l4*8 + s*32 + i
  bf16x8 b[2][8];
#pragma unroll
  for (int cf = 0; cf < 2; ++cf) {
    const uint16_t* bp = Wbf + (Cw + cf * 16 + l15) * 256 + l4 * 8;
#pragma unroll
    for (int s = 0; s < 8; ++s)
      b[cf][s] = *reinterpret_cast<const bf16x8*>(bp + s * 32);
  }

  f32x4 acc[2][2] = {};
  __syncthreads();

#pragma unroll
  for (int s = 0; s < 8; ++s) {
    bf16x8 a0 = *reinterpret_cast<const bf16x8*>(&Alds[lds_addr(Rw + l15,      s * 4 + l4)]);
    bf16x8 a1 = *reinterpret_cast<const bf16x8*>(&Alds[lds_addr(Rw + 16 + l15, s * 4 + l4)]);
    acc[0][0] = __builtin_amdgcn_mfma_f32_16x16x32_bf16(a0, b[0][s], acc[0][0], 0, 0, 0);
    acc[0][1] = __builtin_amdgcn_mfma_f32_16x16x32_bf16(a0, b[1][s], acc[0][1], 0, 0, 0);
    acc[1][0] = __builtin_amdgcn_mfma_f32_16x16x32_bf16(a1, b[0][s], acc[1][0], 0, 0, 0);
    acc[1][1] = __builtin_amdgcn_mfma_f32_16x16x32_bf16(a1, b[1][s], acc[1][1], 0, 0, 0);
  }

  // epilogue: D row = Rw + rf*16 + l4*4 + reg ; col = Cw + cf*16 + l15
#pragma unroll
  for (int rf = 0; rf < 2; ++rf) {
#pragma unroll
    for (int reg = 0; reg < 4; ++reg) {
      int grow = r0 + Rw + rf * 16 + l4 * 4 + reg;
      int ni = nidx[lvl_off + grow];
#pragma unroll
      for (int cf = 0; cf < 2; ++cf) {
        int col = Cw + cf * 16 + l15;
        float v = acc[rf][cf][reg] + bias[col] + Wnon[ni * 128 + col];
        Y[(size_t)grow * 128 + col] = f2bf(tanhf(v));
      }
    }
  }
}

// ---- generic level: X = prev states viewed (n,256) bf16 ----
__global__ __launch_bounds__(512, 8)
void level_kernel(const uint16_t* __restrict__ X, uint16_t* __restrict__ Y,
                  const uint16_t* __restrict__ Wbf, const float* __restrict__ Wnon,
                  const float* __restrict__ bias, const int* __restrict__ nidx,
                  int lvl_off)
{
  __shared__ uint8_t Alds[32768];
  const int tid = threadIdx.x;
  const int r0 = blockIdx.x * 64;
  const uint8_t* Xb = reinterpret_cast<const uint8_t*>(X) + (size_t)r0 * 512;
#pragma unroll
  for (int i = 0; i < 4; ++i) {
    int d = i * 512 + tid;                 // 16B chunk index, 2048 total
    int4 v = *reinterpret_cast<const int4*>(Xb + d * 16);
    *reinterpret_cast<int4*>(&Alds[lds_addr(d >> 5, d & 31)]) = v;
  }
  mfma_tile(Alds, Wbf, Wnon, bias, nidx, lvl_off, r0, Y);
}

// ---- leaf level: gather bf16 embeddings, stage ----
__global__ __launch_bounds__(512, 8)
void leaf_kernel(const int* __restrict__ pos_idx, const int* __restrict__ wrd_idx,
                 const uint16_t* __restrict__ pos_bf, const uint16_t* __restrict__ wrd_bf,
                 uint16_t* __restrict__ Y, const uint16_t* __restrict__ Wbf,
                 const float* __restrict__ Wnon, const float* __restrict__ bias,
                 const int* __restrict__ nidx)
{
  __shared__ uint8_t Alds[32768];
  const int tid = threadIdx.x;
  const int r0 = blockIdx.x * 64;
  {
    int ll = tid >> 2;                     // local leaf 0..127
    int p  = tid & 3;                      // 64B quarter of the 256B leaf vector
    int leaf = r0 * 2 + ll;
    // quarter 0,1 = pos row halves; 2,3 = wrd row halves (each 32 bf16 = 64B)
    const uint16_t* src = (p < 2) ? (pos_bf + (size_t)pos_idx[leaf] * 64 + p * 32)
                                  : (wrd_bf + (size_t)wrd_idx[leaf] * 64 + (p - 2) * 32);
    int arow = ll >> 1;
    int cbase = (ll & 1) * 16 + p * 4;     // 16B-chunk index base within A row
#pragma unroll
    for (int ch = 0; ch < 4; ++ch) {
      int4 v = reinterpret_cast<const int4*>(src)[ch];
      *reinterpret_cast<int4*>(&Alds[lds_addr(arow, cbase + ch)]) = v;
    }
  }
  mfma_tile(Alds, Wbf, Wnon, bias, nidx, /*lvl_off=*/0, r0, Y);
}

// ---- tail: levels n=128..1 in ONE block, states ping-pong in LDS ----
__global__ __launch_bounds__(512, 1)
void tail_kernel(const uint16_t* __restrict__ X, const uint16_t* __restrict__ Wbf,
                 const float* __restrict__ Wnon, const float* __restrict__ bias,
                 const int* __restrict__ nidx, int base_off, float* __restrict__ out)
{
  __shared__ uint8_t P[98304];             // buf0 @0 (64KB), buf1 @65536 (32KB)
  const int tid = threadIdx.x;
  // stage n=128 level input: 256 prev rows = 128 A-rows x 512B = 64KB
#pragma unroll
  for (int i = 0; i < 8; ++i) {
    int d = i * 512 + tid;                 // 4096 chunks
    int4 v = *reinterpret_cast<const int4*>(reinterpret_cast<const uint8_t*>(X) + d * 16);
    *reinterpret_cast<int4*>(&P[lds_addr(d >> 5, d & 31)]) = v;
  }
  const int w = tid >> 6, lane = tid & 63;
  const int Rw = (w >> 2) * 32, Cw = (w & 3) * 32;
  const int l15 = lane & 15, l4 = lane >> 4;
  bf16x8 b[2][8];
#pragma unroll
  for (int cf = 0; cf < 2; ++cf) {
    const uint16_t* bp = Wbf + (Cw + cf * 16 + l15) * 256 + l4 * 8;
#pragma unroll
    for (int s = 0; s < 8; ++s)
      b[cf][s] = *reinterpret_cast<const bf16x8*>(bp + s * 32);
  }
  __syncthreads();

  int off = base_off;
  int cur = 0;
  const int bufoff[2] = {0, 65536};
  for (int n = 128; n >= 1; n >>= 1) {
    const uint8_t* Pin = &P[bufoff[cur]];
    uint8_t* Pout = &P[bufoff[cur ^ 1]];
    int ntiles = (n > 64) ? 2 : 1;
    for (int rt = 0; rt < ntiles; ++rt) {
      int rbase = rt * 64;
      f32x4 acc[2][2] = {};
#pragma unroll
      for (int s = 0; s < 8; ++s) {
        bf16x8 a0 = *reinterpret_cast<const bf16x8*>(&Pin[lds_addr(rbase + Rw + l15,      s * 4 + l4)]);
        bf16x8 a1 = *reinterpret_cast<const bf16x8*>(&Pin[lds_addr(rbase + Rw + 16 + l15, s * 4 + l4)]);
        acc[0][0] = __builtin_amdgcn_mfma_f32_16x16x32_bf16(a0, b[0][s], acc[0][0], 0, 0, 0);
        acc[0][1] = __builtin_amdgcn_mfma_f32_16x16x32_bf16(a0, b[1][s], acc[0][1], 0, 0, 0);
        acc[1][0] = __builtin_amdgcn_mfma_f32_16x16x32_bf16(a1, b[0][s], acc[1][0], 0, 0, 0);
        acc[1][1] = __builtin_amdgcn_mfma_f32_16x16x32_bf16(a1, b[1][s], acc[1][1], 0, 0, 0);
      }
#pragma unroll
      for (int rf = 0; rf < 2; ++rf) {
#pragma unroll
        for (int reg = 0; reg < 4; ++reg) {
          int rl = rbase + Rw + rf * 16 + l4 * 4 + reg;     // global out row in level
          int rcl = rl < (n - 1) ? rl : (n - 1);            // clamp idx read (garbage rows)
          int ni = nidx[off + rcl];
#pragma unroll
          for (int cf = 0; cf < 2; ++cf) {
            int col = Cw + cf * 16 + l15;
            float v = acc[rf][cf][reg] + bias[col] + Wnon[ni * 128 + col];
            float y = tanhf(v);
            if (n == 1) {
              if (rl == 0) out[col] = y;                    // final output fp32
            } else if (rl < n) {
              // write Y row rl into next level's A layout: row rl>>1, colA=(rl&1)*128+col
              int r2 = rl >> 1;
              int colA = (rl & 1) * 128 + col;
              int addr = r2 * 512 + ((((colA >> 3) ^ (r2 & 7))) << 4) + (colA & 7) * 2;
              *reinterpret_cast<uint16_t*>(&Pout[addr]) = f2bf(y);
            }
          }
        }
      }
    }
    off += n;
    cur ^= 1;
    __syncthreads();
  }
}

// ---- prep: convert Wc_w / Wpos / Wwrd fp32 -> bf16 (layouts unchanged) ----
// group g = 8 floats. Wc_w: 4096 groups; Wpos: 512; Wwrd: 800000. Total 804608.
__global__ void prep_all(const float* __restrict__ Wc_w, const float* __restrict__ Wpos,
                         const float* __restrict__ Wwrd, uint16_t* __restrict__ wc_bf,
                         uint16_t* __restrict__ pos_bf, uint16_t* __restrict__ wrd_bf)
{
  int g = blockIdx.x * 256 + threadIdx.x;
  const float* src; uint16_t* dst; int idx;
  if (g < 4096)      { src = Wc_w; dst = wc_bf;  idx = g; }
  else if (g < 4608) { src = Wpos; dst = pos_bf; idx = g - 4096; }
  else               { src = Wwrd; dst = wrd_bf; idx = g - 4608; }
  float4 f0 = reinterpret_cast<const float4*>(src)[idx * 2];
  float4 f1 = reinterpret_cast<const float4*>(src)[idx * 2 + 1];
  union { int4 v; uint16_t u[8]; } pk;
  pk.u[0] = f2bf(f0.x); pk.u[1] = f2bf(f0.y); pk.u[2] = f2bf(f0.z); pk.u[3] = f2bf(f0.w);
  pk.u[4] = f2bf(f1.x); pk.u[5] = f2bf(f1.y); pk.u[6] = f2bf(f1.z); pk.u[7] = f2bf(f1.w);
  reinterpret_cast<int4*>(dst)[idx] = pk.v;
}

extern "C" void kernel_launch(void* const* d_in, const int* in_sizes, int n_in,
                              void* d_out, int out_size, void* d_ws, size_t ws_size,
                              hipStream_t stream)
{
  const int*   pos_idx = (const int*)d_in[0];
  const int*   wrd_idx = (const int*)d_in[1];
  const int*   non_idx = (const int*)d_in[2];
  const float* Wwrd    = (const float*)d_in[3];
  const float* Wpos    = (const float*)d_in[4];
  const float* Wnon    = (const float*)d_in[5];
  const float* Wc_w    = (const float*)d_in[6];
  const float* Wc_b    = (const float*)d_in[7];
  float* out = (float*)d_out;

  uint8_t* ws = (uint8_t*)d_ws;
  uint16_t* Wbf    = (uint16_t*)ws;                               // 64 KiB
  uint16_t* pos_bf = (uint16_t*)(ws + 65536);                     // 8 KiB
  uint16_t* wrd_bf = (uint16_t*)(ws + 65536 + 8192);              // 12.8 MB
  uint8_t*  sbase  = ws + 65536 + 8192 + 12800000;                // states
  uint16_t* S1 = (uint16_t*)sbase;                                // 64 MiB
  uint16_t* S2 = (uint16_t*)(sbase + 67108864);                   // 32 MiB

  prep_all<<<3143, 256, 0, stream>>>(Wc_w, Wpos, Wwrd, Wbf, pos_bf, wrd_bf);

  // level n=262144 (leaf-fused): out -> S1
  leaf_kernel<<<4096, 512, 0, stream>>>(pos_idx, wrd_idx, pos_bf, wrd_bf,
                                        S1, Wbf, Wnon, Wc_b, non_idx);
  int off = 262144;
  uint16_t* bufs[2] = {S1, S2};
  int curb = 0;
  for (int n = 131072; n >= 256; n >>= 1) {
    level_kernel<<<n / 64, 512, 0, stream>>>(bufs[curb], bufs[curb ^ 1],
                                             Wbf, Wnon, Wc_b, non_idx, off);
    off += n;
    curb ^= 1;
  }
  // tail: levels 128..1 in one block; reads n=256 output (in bufs[curb])
  tail_kernel<<<1, 512, 0, stream>>>(bufs[curb], Wbf, Wnon, Wc_b, non_idx, off, out);
}

// Round 3
// 312.520 us; speedup vs baseline: 1.1918x; 1.1918x over previous
//
#include <hip/hip_runtime.h>
#include <stdint.h>

typedef __attribute__((ext_vector_type(8))) __bf16 bf16x8;
typedef __attribute__((ext_vector_type(4))) float f32x4;

#define MFMA __builtin_amdgcn_mfma_f32_16x16x32_bf16

// fp32 -> bf16 round-to-nearest-even
__device__ __forceinline__ uint16_t f2bf(float f) {
  uint32_t u = __float_as_uint(f);
  return (uint16_t)((u + 0x7fffu + ((u >> 16) & 1u)) >> 16);
}

// Swizzled LDS byte address for A-tiles: row-major [rows][256] bf16 (512 B/row),
// 16B chunks XORed by (row&7) (T2) to kill 512B-stride bank conflicts.
__device__ __forceinline__ int lds_addr(int row, int chunk) {
  return row * 512 + ((chunk ^ (row & 7)) << 4);
}

__device__ __forceinline__ void load_bfrag(const uint16_t* __restrict__ Wbf,
                                           int Cw, int l15, int l4, bf16x8 bf[2][8]) {
#pragma unroll
  for (int cf = 0; cf < 2; ++cf) {
    const uint16_t* bp = Wbf + (Cw + cf * 16 + l15) * 256 + l4 * 8;
#pragma unroll
    for (int s = 0; s < 8; ++s)
      bf[cf][s] = *reinterpret_cast<const bf16x8*>(bp + s * 32);
  }
}

// ---- fused 2-level kernel ----
// Block b0 computes 64 rows of level-2 from 128 rows of level-1 from 256 inputs.
// LEAF: level-1 A comes from embedding gather; else from global X (prev states).
// GEMM1 A goes global->register (no LDS); level-1 out -> Mid (A-layout, swizzled);
// GEMM2 from Mid; out staged in OutS then stored coalesced (32B/thread).
template<bool LEAF>
__global__ __launch_bounds__(512, 4)
void fused2_kernel(const uint16_t* __restrict__ X,
                   const int* __restrict__ pos_idx, const int* __restrict__ wrd_idx,
                   const uint16_t* __restrict__ pos_bf, const uint16_t* __restrict__ wrd_bf,
                   uint16_t* __restrict__ Y, const uint16_t* __restrict__ Wbf,
                   const float* __restrict__ Wnon, const float* __restrict__ bias,
                   const int* __restrict__ nidx, int off1, int off2)
{
  __shared__ uint8_t Mid[32768];
  __shared__ uint8_t OutS[16384];
  const int tid = threadIdx.x, w = tid >> 6, lane = tid & 63;
  const int Rw = (w >> 2) * 32, Cw = (w & 3) * 32;
  const int l15 = lane & 15, l4 = lane >> 4;
  const int b0 = blockIdx.x;

  bf16x8 bfrag[2][8];
  load_bfrag(Wbf, Cw, l15, l4, bfrag);

  // ---- GEMM1: two 64-row tiles of level-1 ----
#pragma unroll
  for (int t = 0; t < 2; ++t) {
    const int g1a = b0 * 128 + t * 64 + Rw + l15;
    const int g1b = g1a + 16;
    int p0a = 0, p1a = 0, w0a = 0, w1a = 0, p0b = 0, p1b = 0, w0b = 0, w1b = 0;
    const uint16_t *Xa = nullptr, *Xb = nullptr;
    if (LEAF) {
      p0a = pos_idx[2 * g1a];     p1a = pos_idx[2 * g1a + 1];
      w0a = wrd_idx[2 * g1a];     w1a = wrd_idx[2 * g1a + 1];
      p0b = pos_idx[2 * g1b];     p1b = pos_idx[2 * g1b + 1];
      w0b = wrd_idx[2 * g1b];     w1b = wrd_idx[2 * g1b + 1];
    } else {
      Xa = X + (size_t)g1a * 256 + l4 * 8;
      Xb = X + (size_t)g1b * 256 + l4 * 8;
    }
    f32x4 acc[2][2] = {};
#pragma unroll
    for (int s = 0; s < 8; ++s) {
      bf16x8 a0, a1;
      if (LEAF) {
        // A-row g1: k<128 = left leaf (2*g1), k>=128 = right (2*g1+1);
        // within leaf: first 64 dims = pos table, next 64 = wrd table.
        const int o = (s & 1) * 32 + l4 * 8;
        if (!(s & 2)) {
          const int ia = (s < 4) ? p0a : p1a;
          const int ib = (s < 4) ? p0b : p1b;
          a0 = *reinterpret_cast<const bf16x8*>(pos_bf + (size_t)ia * 64 + o);
          a1 = *reinterpret_cast<const bf16x8*>(pos_bf + (size_t)ib * 64 + o);
        } else {
          const int ia = (s < 4) ? w0a : w1a;
          const int ib = (s < 4) ? w0b : w1b;
          a0 = *reinterpret_cast<const bf16x8*>(wrd_bf + (size_t)ia * 64 + o);
          a1 = *reinterpret_cast<const bf16x8*>(wrd_bf + (size_t)ib * 64 + o);
        }
      } else {
        a0 = *reinterpret_cast<const bf16x8*>(Xa + s * 32);
        a1 = *reinterpret_cast<const bf16x8*>(Xb + s * 32);
      }
      acc[0][0] = MFMA(a0, bfrag[0][s], acc[0][0], 0, 0, 0);
      acc[0][1] = MFMA(a0, bfrag[1][s], acc[0][1], 0, 0, 0);
      acc[1][0] = MFMA(a1, bfrag[0][s], acc[1][0], 0, 0, 0);
      acc[1][1] = MFMA(a1, bfrag[1][s], acc[1][1], 0, 0, 0);
    }
    // epilogue -> Mid as next level's A-layout: row r1 -> A-row r1>>1, colA=(r1&1)*128+col
#pragma unroll
    for (int rf = 0; rf < 2; ++rf) {
#pragma unroll
      for (int reg = 0; reg < 4; ++reg) {
        const int r1 = t * 64 + Rw + rf * 16 + l4 * 4 + reg;
        const int ni = nidx[off1 + b0 * 128 + r1];
#pragma unroll
        for (int cf = 0; cf < 2; ++cf) {
          const int col = Cw + cf * 16 + l15;
          const float v = acc[rf][cf][reg] + bias[col] + Wnon[ni * 128 + col];
          const int r2 = r1 >> 1;
          const int colA = (r1 & 1) * 128 + col;
          *reinterpret_cast<uint16_t*>(
              &Mid[r2 * 512 + (((colA >> 3) ^ (r2 & 7)) << 4) + (colA & 7) * 2]) =
              f2bf(tanhf(v));
        }
      }
    }
  }
  __syncthreads();

  // ---- GEMM2 from Mid ----
  {
    f32x4 acc[2][2] = {};
#pragma unroll
    for (int s = 0; s < 8; ++s) {
      bf16x8 a0 = *reinterpret_cast<const bf16x8*>(&Mid[lds_addr(Rw + l15,      s * 4 + l4)]);
      bf16x8 a1 = *reinterpret_cast<const bf16x8*>(&Mid[lds_addr(Rw + 16 + l15, s * 4 + l4)]);
      acc[0][0] = MFMA(a0, bfrag[0][s], acc[0][0], 0, 0, 0);
      acc[0][1] = MFMA(a0, bfrag[1][s], acc[0][1], 0, 0, 0);
      acc[1][0] = MFMA(a1, bfrag[0][s], acc[1][0], 0, 0, 0);
      acc[1][1] = MFMA(a1, bfrag[1][s], acc[1][1], 0, 0, 0);
    }
#pragma unroll
    for (int rf = 0; rf < 2; ++rf) {
#pragma unroll
      for (int reg = 0; reg < 4; ++reg) {
        const int row = Rw + rf * 16 + l4 * 4 + reg;
        const int ni = nidx[off2 + b0 * 64 + row];
#pragma unroll
        for (int cf = 0; cf < 2; ++cf) {
          const int col = Cw + cf * 16 + l15;
          const float v = acc[rf][cf][reg] + bias[col] + Wnon[ni * 128 + col];
          const int colb = col * 2;
          *reinterpret_cast<uint16_t*>(
              &OutS[row * 256 + (((colb >> 4) ^ (row & 7)) << 4) + (colb & 15)]) =
              f2bf(tanhf(v));
        }
      }
    }
  }
  __syncthreads();

  // ---- coalesced store: 512 threads x 32B contiguous (full lines, no RFO) ----
  {
    const int row = tid >> 3, c2 = (tid & 7) * 2;
    int4 v0 = *reinterpret_cast<const int4*>(&OutS[row * 256 + ((c2       ^ (row & 7)) << 4)]);
    int4 v1 = *reinterpret_cast<const int4*>(&OutS[row * 256 + (((c2 + 1) ^ (row & 7)) << 4)]);
    uint8_t* dst = reinterpret_cast<uint8_t*>(Y) + ((size_t)b0 * 64 + row) * 256 + c2 * 16;
    *reinterpret_cast<int4*>(dst) = v0;
    *reinterpret_cast<int4*>(dst + 16) = v1;
  }
}

// ---- tail: levels n=256..1 in ONE block ----
// n=256 reads A from global (512 input rows); rest ping-pong in LDS.
__global__ __launch_bounds__(512, 1)
void tail_kernel(const uint16_t* __restrict__ X, const uint16_t* __restrict__ Wbf,
                 const float* __restrict__ Wnon, const float* __restrict__ bias,
                 const int* __restrict__ nidx, int base_off, float* __restrict__ out)
{
  __shared__ uint8_t P[98304];   // buf0 @0 (64KB), buf1 @65536 (32KB)
  const int tid = threadIdx.x, w = tid >> 6, lane = tid & 63;
  const int Rw = (w >> 2) * 32, Cw = (w & 3) * 32;
  const int l15 = lane & 15, l4 = lane >> 4;

  bf16x8 bfrag[2][8];
  load_bfrag(Wbf, Cw, l15, l4, bfrag);

  int off = base_off;

  // ---- n=256 from global ----
  for (int t = 0; t < 4; ++t) {
    f32x4 acc[2][2] = {};
    const uint16_t* Xa = X + (size_t)(t * 64 + Rw + l15) * 256 + l4 * 8;
    const uint16_t* Xb = Xa + 16 * 256;
#pragma unroll
    for (int s = 0; s < 8; ++s) {
      bf16x8 a0 = *reinterpret_cast<const bf16x8*>(Xa + s * 32);
      bf16x8 a1 = *reinterpret_cast<const bf16x8*>(Xb + s * 32);
      acc[0][0] = MFMA(a0, bfrag[0][s], acc[0][0], 0, 0, 0);
      acc[0][1] = MFMA(a0, bfrag[1][s], acc[0][1], 0, 0, 0);
      acc[1][0] = MFMA(a1, bfrag[0][s], acc[1][0], 0, 0, 0);
      acc[1][1] = MFMA(a1, bfrag[1][s], acc[1][1], 0, 0, 0);
    }
#pragma unroll
    for (int rf = 0; rf < 2; ++rf) {
#pragma unroll
      for (int reg = 0; reg < 4; ++reg) {
        const int r1 = t * 64 + Rw + rf * 16 + l4 * 4 + reg;
        const int ni = nidx[off + r1];
#pragma unroll
        for (int cf = 0; cf < 2; ++cf) {
          const int col = Cw + cf * 16 + l15;
          const float v = acc[rf][cf][reg] + bias[col] + Wnon[ni * 128 + col];
          const int r2 = r1 >> 1;
          const int colA = (r1 & 1) * 128 + col;
          *reinterpret_cast<uint16_t*>(
              &P[r2 * 512 + (((colA >> 3) ^ (r2 & 7)) << 4) + (colA & 7) * 2]) =
              f2bf(tanhf(v));
        }
      }
    }
  }
  off += 256;
  __syncthreads();

  int cur = 0;                                  // A for n=128 lives in buf0
  for (int n = 128; n >= 1; n >>= 1) {
    const uint8_t* Pin = P + (cur ? 65536 : 0);
    uint8_t* Pout = P + (cur ? 0 : 65536);
    const int ntiles = (n + 63) >> 6;
    for (int t = 0; t < ntiles; ++t) {
      f32x4 acc[2][2] = {};
#pragma unroll
      for (int s = 0; s < 8; ++s) {
        bf16x8 a0 = *reinterpret_cast<const bf16x8*>(&Pin[lds_addr(t * 64 + Rw + l15,      s * 4 + l4)]);
        bf16x8 a1 = *reinterpret_cast<const bf16x8*>(&Pin[lds_addr(t * 64 + Rw + 16 + l15, s * 4 + l4)]);
        acc[0][0] = MFMA(a0, bfrag[0][s], acc[0][0], 0, 0, 0);
        acc[0][1] = MFMA(a0, bfrag[1][s], acc[0][1], 0, 0, 0);
        acc[1][0] = MFMA(a1, bfrag[0][s], acc[1][0], 0, 0, 0);
        acc[1][1] = MFMA(a1, bfrag[1][s], acc[1][1], 0, 0, 0);
      }
#pragma unroll
      for (int rf = 0; rf < 2; ++rf) {
#pragma unroll
        for (int reg = 0; reg < 4; ++reg) {
          const int rl = t * 64 + Rw + rf * 16 + l4 * 4 + reg;
          const int rcl = rl < n ? rl : n - 1;          // clamp idx for garbage rows
          const int ni = nidx[off + rcl];
#pragma unroll
          for (int cf = 0; cf < 2; ++cf) {
            const int col = Cw + cf * 16 + l15;
            const float v = acc[rf][cf][reg] + bias[col] + Wnon[ni * 128 + col];
            const float y = tanhf(v);
            if (n == 1) {
              if (rl == 0) out[col] = y;
            } else if (rl < n) {
              const int r2 = rl >> 1;
              const int colA = (rl & 1) * 128 + col;
              *reinterpret_cast<uint16_t*>(
                  &Pout[r2 * 512 + (((colA >> 3) ^ (r2 & 7)) << 4) + (colA & 7) * 2]) =
                  f2bf(y);
            }
          }
        }
      }
    }
    off += n;
    cur ^= 1;
    __syncthreads();
  }
}

// ---- prep: convert Wc_w / Wpos / Wwrd fp32 -> bf16 (layouts unchanged) ----
__global__ void prep_all(const float* __restrict__ Wc_w, const float* __restrict__ Wpos,
                         const float* __restrict__ Wwrd, uint16_t* __restrict__ wc_bf,
                         uint16_t* __restrict__ pos_bf, uint16_t* __restrict__ wrd_bf)
{
  int g = blockIdx.x * 256 + threadIdx.x;       // one 8-float group each
  const float* src; uint16_t* dst; int idx;
  if (g < 4096)      { src = Wc_w; dst = wc_bf;  idx = g; }
  else if (g < 4608) { src = Wpos; dst = pos_bf; idx = g - 4096; }
  else               { src = Wwrd; dst = wrd_bf; idx = g - 4608; }
  float4 f0 = reinterpret_cast<const float4*>(src)[idx * 2];
  float4 f1 = reinterpret_cast<const float4*>(src)[idx * 2 + 1];
  union { int4 v; uint16_t u[8]; } pk;
  pk.u[0] = f2bf(f0.x); pk.u[1] = f2bf(f0.y); pk.u[2] = f2bf(f0.z); pk.u[3] = f2bf(f0.w);
  pk.u[4] = f2bf(f1.x); pk.u[5] = f2bf(f1.y); pk.u[6] = f2bf(f1.z); pk.u[7] = f2bf(f1.w);
  reinterpret_cast<int4*>(dst)[idx] = pk.v;
}

extern "C" void kernel_launch(void* const* d_in, const int* in_sizes, int n_in,
                              void* d_out, int out_size, void* d_ws, size_t ws_size,
                              hipStream_t stream)
{
  const int*   pos_idx = (const int*)d_in[0];
  const int*   wrd_idx = (const int*)d_in[1];
  const int*   non_idx = (const int*)d_in[2];
  const float* Wwrd    = (const float*)d_in[3];
  const float* Wpos    = (const float*)d_in[4];
  const float* Wnon    = (const float*)d_in[5];
  const float* Wc_w    = (const float*)d_in[6];
  const float* Wc_b    = (const float*)d_in[7];
  float* out = (float*)d_out;

  uint8_t* ws = (uint8_t*)d_ws;
  uint16_t* Wbf    = (uint16_t*)ws;                               // 64 KiB
  uint16_t* pos_bf = (uint16_t*)(ws + 65536);                     // 8 KiB
  uint16_t* wrd_bf = (uint16_t*)(ws + 65536 + 8192);              // 12.8 MB
  uint16_t* S1     = (uint16_t*)(ws + 12873728);                  // 33.6 MB (131072x128 bf16)
  uint16_t* S2     = (uint16_t*)(ws + 46428160);                  // 8.4 MB  (32768x128 bf16)

  prep_all<<<3143, 256, 0, stream>>>(Wc_w, Wpos, Wwrd, Wbf, pos_bf, wrd_bf);

  // Level offsets into non_idx: L1=0(262144), L2=262144(131072), L3=393216(65536),
  // L4=458752(32768), L5=491520(16384), L6=507904(8192), L7=516096(4096),
  // L8=520192(2048), L9=522240(1024), L10=523264(512), tail from 523776(256..1).

  // leaf + L1 + L2 fused: gather -> 262144 -> 131072 rows
  fused2_kernel<true><<<2048, 512, 0, stream>>>(nullptr, pos_idx, wrd_idx, pos_bf, wrd_bf,
                                                S1, Wbf, Wnon, Wc_b, non_idx, 0, 262144);
  // L3+L4: 131072 -> 65536 -> 32768
  fused2_kernel<false><<<512, 512, 0, stream>>>(S1, nullptr, nullptr, nullptr, nullptr,
                                                S2, Wbf, Wnon, Wc_b, non_idx, 393216, 458752);
  // L5+L6: 32768 -> 16384 -> 8192
  fused2_kernel<false><<<128, 512, 0, stream>>>(S2, nullptr, nullptr, nullptr, nullptr,
                                                S1, Wbf, Wnon, Wc_b, non_idx, 491520, 507904);
  // L7+L8: 8192 -> 4096 -> 2048
  fused2_kernel<false><<<32, 512, 0, stream>>>(S1, nullptr, nullptr, nullptr, nullptr,
                                               S2, Wbf, Wnon, Wc_b, non_idx, 516096, 520192);
  // L9+L10: 2048 -> 1024 -> 512
  fused2_kernel<false><<<8, 512, 0, stream>>>(S2, nullptr, nullptr, nullptr, nullptr,
                                              S1, Wbf, Wnon, Wc_b, non_idx, 522240, 523264);
  // tail: 256..1 (reads 512 rows in S1)
  tail_kernel<<<1, 512, 0, stream>>>(S1, Wbf, Wnon, Wc_b, non_idx, 523776, out);
}

// Round 4
// 271.781 us; speedup vs baseline: 1.3704x; 1.1499x over previous
//
#include <hip/hip_runtime.h>
#include <stdint.h>

typedef __attribute__((ext_vector_type(8))) __bf16 bf16x8;
typedef __attribute__((ext_vector_type(4))) float f32x4;

#define MFMA __builtin_amdgcn_mfma_f32_16x16x32_bf16

// fp32 -> bf16 round-to-nearest-even
__device__ __forceinline__ uint16_t f2bf(float f) {
  uint32_t u = __float_as_uint(f);
  return (uint16_t)((u + 0x7fffu + ((u >> 16) & 1u)) >> 16);
}

// Swizzled LDS byte address for A-tiles: row-major [rows][256] bf16 (512 B/row),
// 16B chunks XORed by (row&7) (T2) to kill 512B-stride bank conflicts.
__device__ __forceinline__ int lds_addr(int row, int chunk) {
  return row * 512 + ((chunk ^ (row & 7)) << 4);
}

__device__ __forceinline__ void load_bfrag(const uint16_t* __restrict__ Wbf,
                                           int Cw, int l15, int l4, bf16x8 bf[2][8]) {
#pragma unroll
  for (int cf = 0; cf < 2; ++cf) {
    const uint16_t* bp = Wbf + (Cw + cf * 16 + l15) * 256 + l4 * 8;
#pragma unroll
    for (int s = 0; s < 8; ++s)
      bf[cf][s] = *reinterpret_cast<const bf16x8*>(bp + s * 32);
  }
}

__device__ __forceinline__ void gemm_lds(const uint8_t* base, const bf16x8 bfrag[2][8],
                                         int Rw, int Cw, int l15, int l4, f32x4 acc[2][2]) {
#pragma unroll
  for (int s = 0; s < 8; ++s) {
    bf16x8 a0 = *reinterpret_cast<const bf16x8*>(&base[lds_addr(Rw + l15,      s * 4 + l4)]);
    bf16x8 a1 = *reinterpret_cast<const bf16x8*>(&base[lds_addr(Rw + 16 + l15, s * 4 + l4)]);
    acc[0][0] = MFMA(a0, bfrag[0][s], acc[0][0], 0, 0, 0);
    acc[0][1] = MFMA(a0, bfrag[1][s], acc[0][1], 0, 0, 0);
    acc[1][0] = MFMA(a1, bfrag[0][s], acc[1][0], 0, 0, 0);
    acc[1][1] = MFMA(a1, bfrag[1][s], acc[1][1], 0, 0, 0);
  }
}

// ---- fused 2-level kernel ----
// Block b0: 256 inputs -> 128 L1 rows (2 tiles) -> 64 L2 rows.
// A tiles (both) cooperatively staged into LDS in ONE up-front async batch
// (pre-swizzled source -> linear LDS; reads use the same XOR involution).
// LDS overlay: Abuf[0:32K)=A0 then Mid; Abuf[32K:64K)=A1 then OutS.
template<bool LEAF>
__global__ __launch_bounds__(512, 2)
void fused2_kernel(const uint16_t* __restrict__ X,
                   const int* __restrict__ pos_idx, const int* __restrict__ wrd_idx,
                   const uint16_t* __restrict__ pos_bf, const uint16_t* __restrict__ wrd_bf,
                   uint16_t* __restrict__ Y, const uint16_t* __restrict__ Wbf,
                   const float* __restrict__ Wnon, const float* __restrict__ bias,
                   const int* __restrict__ nidx, int off1, int off2)
{
  __shared__ uint8_t Abuf[65536];
  const int tid = threadIdx.x, w = tid >> 6, lane = tid & 63;
  const int Rw = (w >> 2) * 32, Cw = (w & 3) * 32;
  const int l15 = lane & 15, l4 = lane >> 4;
  const int b0 = blockIdx.x;

  // ---- stage BOTH A tiles: 4096 x 16B chunks, 8 per thread, all issued up front ----
  int4 stg[8];
#pragma unroll
  for (int k = 0; k < 8; ++k) {
    const int cg = tid + k * 512;            // global chunk id [0,4096)
    const int t = cg >> 11;                  // tile 0/1
    const int ct = cg & 2047;                // chunk within tile
    const int arow = ct >> 5;                // A-row [0,64)
    const int c = (ct & 31) ^ (arow & 7);    // logical 16B chunk (pre-swizzled source)
    if (LEAF) {
      // A-row layout: [pos(leafL)|wrd(leafL)|pos(leafR)|wrd(leafR)], 8 chunks each
      const int seg = c >> 3;
      const int leaf = 2 * (b0 * 128 + t * 64 + arow) + (seg >> 1);
      const int idx = (seg & 1) ? wrd_idx[leaf] : pos_idx[leaf];
      const uint16_t* tab = (seg & 1) ? wrd_bf : pos_bf;
      stg[k] = *reinterpret_cast<const int4*>(tab + (size_t)idx * 64 + (c & 7) * 8);
    } else {
      stg[k] = *reinterpret_cast<const int4*>(
          reinterpret_cast<const uint8_t*>(X) +
          (((size_t)(b0 * 128 + t * 64 + arow)) << 9) + (c << 4));
    }
  }

  bf16x8 bfrag[2][8];
  load_bfrag(Wbf, Cw, l15, l4, bfrag);

#pragma unroll
  for (int k = 0; k < 8; ++k)
    *reinterpret_cast<int4*>(&Abuf[(tid + k * 512) << 4]) = stg[k];

  __syncthreads();                           // staging complete

  // ---- GEMM1 tile 0 (A0 = Abuf[0:32K)) ----
  f32x4 acc0[2][2] = {}, acc1[2][2] = {};
  gemm_lds(Abuf, bfrag, Rw, Cw, l15, l4, acc0);
  __syncthreads();                           // A0 reads done; Mid may overlay A0

  // ---- GEMM1 tile 1 (A1 = Abuf[32K:64K)) ----
  gemm_lds(Abuf + 32768, bfrag, Rw, Cw, l15, l4, acc1);

  // ---- epilogue tiles 0,1 -> Mid (= Abuf[0:32K), next-level A layout, swizzled) ----
#pragma unroll
  for (int t = 0; t < 2; ++t) {
    const f32x4 (*acc)[2] = t ? acc1 : acc0;
#pragma unroll
    for (int rf = 0; rf < 2; ++rf) {
#pragma unroll
      for (int reg = 0; reg < 4; ++reg) {
        const int r1 = t * 64 + Rw + rf * 16 + l4 * 4 + reg;  // [0,128)
        const int ni = nidx[off1 + b0 * 128 + r1];
#pragma unroll
        for (int cf = 0; cf < 2; ++cf) {
          const int col = Cw + cf * 16 + l15;
          const float v = acc[rf][cf][reg] + bias[col] + Wnon[ni * 128 + col];
          const int r2 = r1 >> 1;
          const int colA = (r1 & 1) * 128 + col;
          *reinterpret_cast<uint16_t*>(
              &Abuf[r2 * 512 + (((colA >> 3) ^ (r2 & 7)) << 4) + (colA & 7) * 2]) =
              f2bf(tanhf(v));
        }
      }
    }
  }
  __syncthreads();                           // Mid complete

  // ---- GEMM2 from Mid; epilogue -> OutS (= Abuf[32K:48K)) ----
  {
    uint8_t* OutS = Abuf + 32768;
    f32x4 acc[2][2] = {};
    gemm_lds(Abuf, bfrag, Rw, Cw, l15, l4, acc);
#pragma unroll
    for (int rf = 0; rf < 2; ++rf) {
#pragma unroll
      for (int reg = 0; reg < 4; ++reg) {
        const int row = Rw + rf * 16 + l4 * 4 + reg;
        const int ni = nidx[off2 + b0 * 64 + row];
#pragma unroll
        for (int cf = 0; cf < 2; ++cf) {
          const int col = Cw + cf * 16 + l15;
          const float v = acc[rf][cf][reg] + bias[col] + Wnon[ni * 128 + col];
          const int colb = col * 2;
          *reinterpret_cast<uint16_t*>(
              &OutS[row * 256 + (((colb >> 4) ^ (row & 7)) << 4) + (colb & 15)]) =
              f2bf(tanhf(v));
        }
      }
    }
  }
  __syncthreads();                           // OutS complete

  // ---- coalesced store: 512 threads x 32B contiguous (full lines, no RFO) ----
  {
    const uint8_t* OutS = Abuf + 32768;
    const int row = tid >> 3, c2 = (tid & 7) * 2;
    int4 v0 = *reinterpret_cast<const int4*>(&OutS[row * 256 + ((c2       ^ (row & 7)) << 4)]);
    int4 v1 = *reinterpret_cast<const int4*>(&OutS[row * 256 + (((c2 + 1) ^ (row & 7)) << 4)]);
    uint8_t* dst = reinterpret_cast<uint8_t*>(Y) + ((size_t)b0 * 64 + row) * 256 + c2 * 16;
    *reinterpret_cast<int4*>(dst) = v0;
    *reinterpret_cast<int4*>(dst + 16) = v1;
  }
}

// ---- tail: levels n=256..1 in ONE block ----
__global__ __launch_bounds__(512, 1)
void tail_kernel(const uint16_t* __restrict__ X, const uint16_t* __restrict__ Wbf,
                 const float* __restrict__ Wnon, const float* __restrict__ bias,
                 const int* __restrict__ nidx, int base_off, float* __restrict__ out)
{
  __shared__ uint8_t P[98304];   // buf0 @0 (64KB), buf1 @65536 (32KB)
  const int tid = threadIdx.x, w = tid >> 6, lane = tid & 63;
  const int Rw = (w >> 2) * 32, Cw = (w & 3) * 32;
  const int l15 = lane & 15, l4 = lane >> 4;

  bf16x8 bfrag[2][8];
  load_bfrag(Wbf, Cw, l15, l4, bfrag);

  int off = base_off;

  // ---- n=256 from global ----
  for (int t = 0; t < 4; ++t) {
    f32x4 acc[2][2] = {};
    const uint16_t* Xa = X + (size_t)(t * 64 + Rw + l15) * 256 + l4 * 8;
    const uint16_t* Xb = Xa + 16 * 256;
#pragma unroll
    for (int s = 0; s < 8; ++s) {
      bf16x8 a0 = *reinterpret_cast<const bf16x8*>(Xa + s * 32);
      bf16x8 a1 = *reinterpret_cast<const bf16x8*>(Xb + s * 32);
      acc[0][0] = MFMA(a0, bfrag[0][s], acc[0][0], 0, 0, 0);
      acc[0][1] = MFMA(a0, bfrag[1][s], acc[0][1], 0, 0, 0);
      acc[1][0] = MFMA(a1, bfrag[0][s], acc[1][0], 0, 0, 0);
      acc[1][1] = MFMA(a1, bfrag[1][s], acc[1][1], 0, 0, 0);
    }
#pragma unroll
    for (int rf = 0; rf < 2; ++rf) {
#pragma unroll
      for (int reg = 0; reg < 4; ++reg) {
        const int r1 = t * 64 + Rw + rf * 16 + l4 * 4 + reg;
        const int ni = nidx[off + r1];
#pragma unroll
        for (int cf = 0; cf < 2; ++cf) {
          const int col = Cw + cf * 16 + l15;
          const float v = acc[rf][cf][reg] + bias[col] + Wnon[ni * 128 + col];
          const int r2 = r1 >> 1;
          const int colA = (r1 & 1) * 128 + col;
          *reinterpret_cast<uint16_t*>(
              &P[r2 * 512 + (((colA >> 3) ^ (r2 & 7)) << 4) + (colA & 7) * 2]) =
              f2bf(tanhf(v));
        }
      }
    }
  }
  off += 256;
  __syncthreads();

  int cur = 0;                                  // A for n=128 lives in buf0
  for (int n = 128; n >= 1; n >>= 1) {
    const uint8_t* Pin = P + (cur ? 65536 : 0);
    uint8_t* Pout = P + (cur ? 0 : 65536);
    const int ntiles = (n + 63) >> 6;
    for (int t = 0; t < ntiles; ++t) {
      f32x4 acc[2][2] = {};
#pragma unroll
      for (int s = 0; s < 8; ++s) {
        bf16x8 a0 = *reinterpret_cast<const bf16x8*>(&Pin[lds_addr(t * 64 + Rw + l15,      s * 4 + l4)]);
        bf16x8 a1 = *reinterpret_cast<const bf16x8*>(&Pin[lds_addr(t * 64 + Rw + 16 + l15, s * 4 + l4)]);
        acc[0][0] = MFMA(a0, bfrag[0][s], acc[0][0], 0, 0, 0);
        acc[0][1] = MFMA(a0, bfrag[1][s], acc[0][1], 0, 0, 0);
        acc[1][0] = MFMA(a1, bfrag[0][s], acc[1][0], 0, 0, 0);
        acc[1][1] = MFMA(a1, bfrag[1][s], acc[1][1], 0, 0, 0);
      }
#pragma unroll
      for (int rf = 0; rf < 2; ++rf) {
#pragma unroll
        for (int reg = 0; reg < 4; ++reg) {
          const int rl = t * 64 + Rw + rf * 16 + l4 * 4 + reg;
          const int rcl = rl < n ? rl : n - 1;          // clamp idx for garbage rows
          const int ni = nidx[off + rcl];
#pragma unroll
          for (int cf = 0; cf < 2; ++cf) {
            const int col = Cw + cf * 16 + l15;
            const float v = acc[rf][cf][reg] + bias[col] + Wnon[ni * 128 + col];
            const float y = tanhf(v);
            if (n == 1) {
              if (rl == 0) out[col] = y;
            } else if (rl < n) {
              const int r2 = rl >> 1;
              const int colA = (rl & 1) * 128 + col;
              *reinterpret_cast<uint16_t*>(
                  &Pout[r2 * 512 + (((colA >> 3) ^ (r2 & 7)) << 4) + (colA & 7) * 2]) =
                  f2bf(y);
            }
          }
        }
      }
    }
    off += n;
    cur ^= 1;
    __syncthreads();
  }
}

// ---- prep: convert Wc_w / Wpos / Wwrd fp32 -> bf16 (layouts unchanged) ----
__global__ void prep_all(const float* __restrict__ Wc_w, const float* __restrict__ Wpos,
                         const float* __restrict__ Wwrd, uint16_t* __restrict__ wc_bf,
                         uint16_t* __restrict__ pos_bf, uint16_t* __restrict__ wrd_bf)
{
  int g = blockIdx.x * 256 + threadIdx.x;       // one 8-float group each
  const float* src; uint16_t* dst; int idx;
  if (g < 4096)      { src = Wc_w; dst = wc_bf;  idx = g; }
  else if (g < 4608) { src = Wpos; dst = pos_bf; idx = g - 4096; }
  else               { src = Wwrd; dst = wrd_bf; idx = g - 4608; }
  float4 f0 = reinterpret_cast<const float4*>(src)[idx * 2];
  float4 f1 = reinterpret_cast<const float4*>(src)[idx * 2 + 1];
  union { int4 v; uint16_t u[8]; } pk;
  pk.u[0] = f2bf(f0.x); pk.u[1] = f2bf(f0.y); pk.u[2] = f2bf(f0.z); pk.u[3] = f2bf(f0.w);
  pk.u[4] = f2bf(f1.x); pk.u[5] = f2bf(f1.y); pk.u[6] = f2bf(f1.z); pk.u[7] = f2bf(f1.w);
  reinterpret_cast<int4*>(dst)[idx] = pk.v;
}

extern "C" void kernel_launch(void* const* d_in, const int* in_sizes, int n_in,
                              void* d_out, int out_size, void* d_ws, size_t ws_size,
                              hipStream_t stream)
{
  const int*   pos_idx = (const int*)d_in[0];
  const int*   wrd_idx = (const int*)d_in[1];
  const int*   non_idx = (const int*)d_in[2];
  const float* Wwrd    = (const float*)d_in[3];
  const float* Wpos    = (const float*)d_in[4];
  const float* Wnon    = (const float*)d_in[5];
  const float* Wc_w    = (const float*)d_in[6];
  const float* Wc_b    = (const float*)d_in[7];
  float* out = (float*)d_out;

  uint8_t* ws = (uint8_t*)d_ws;
  uint16_t* Wbf    = (uint16_t*)ws;                               // 64 KiB
  uint16_t* pos_bf = (uint16_t*)(ws + 65536);                     // 8 KiB
  uint16_t* wrd_bf = (uint16_t*)(ws + 65536 + 8192);              // 12.8 MB
  uint16_t* S1     = (uint16_t*)(ws + 12873728);                  // 33.6 MB (131072x128 bf16)
  uint16_t* S2     = (uint16_t*)(ws + 46428160);                  // 8.4 MB  (32768x128 bf16)

  prep_all<<<3143, 256, 0, stream>>>(Wc_w, Wpos, Wwrd, Wbf, pos_bf, wrd_bf);

  // Level offsets into non_idx: L1=0(262144), L2=262144(131072), L3=393216(65536),
  // L4=458752(32768), L5=491520(16384), L6=507904(8192), L7=516096(4096),
  // L8=520192(2048), L9=522240(1024), L10=523264(512), tail from 523776(256..1).

  // leaf + L1 + L2 fused: gather -> 262144 -> 131072 rows
  fused2_kernel<true><<<2048, 512, 0, stream>>>(nullptr, pos_idx, wrd_idx, pos_bf, wrd_bf,
                                                S1, Wbf, Wnon, Wc_b, non_idx, 0, 262144);
  // L3+L4: 131072 -> 65536 -> 32768
  fused2_kernel<false><<<512, 512, 0, stream>>>(S1, nullptr, nullptr, nullptr, nullptr,
                                                S2, Wbf, Wnon, Wc_b, non_idx, 393216, 458752);
  // L5+L6: 32768 -> 16384 -> 8192
  fused2_kernel<false><<<128, 512, 0, stream>>>(S2, nullptr, nullptr, nullptr, nullptr,
                                                S1, Wbf, Wnon, Wc_b, non_idx, 491520, 507904);
  // L7+L8: 8192 -> 4096 -> 2048
  fused2_kernel<false><<<32, 512, 0, stream>>>(S1, nullptr, nullptr, nullptr, nullptr,
                                               S2, Wbf, Wnon, Wc_b, non_idx, 516096, 520192);
  // L9+L10: 2048 -> 1024 -> 512
  fused2_kernel<false><<<8, 512, 0, stream>>>(S2, nullptr, nullptr, nullptr, nullptr,
                                              S1, Wbf, Wnon, Wc_b, non_idx, 522240, 523264);
  // tail: 256..1 (reads 512 rows in S1)
  tail_kernel<<<1, 512, 0, stream>>>(S1, Wbf, Wnon, Wc_b, non_idx, 523776, out);
}

// Round 5
// 258.152 us; speedup vs baseline: 1.4428x; 1.0528x over previous
//
#include <hip/hip_runtime.h>
#include <stdint.h>

typedef __attribute__((ext_vector_type(8))) __bf16 bf16x8;
typedef __attribute__((ext_vector_type(4))) float f32x4;

#define MFMA __builtin_amdgcn_mfma_f32_16x16x32_bf16

// fp32 -> bf16 round-to-nearest-even
__device__ __forceinline__ uint16_t f2bf(float f) {
  uint32_t u = __float_as_uint(f);
  return (uint16_t)((u + 0x7fffu + ((u >> 16) & 1u)) >> 16);
}

// fast tanh: clamp then (e^2x-1)/(e^2x+1). NaN-safe (fmaxf(NaN,..) -> clamp).
// rel err ~1e-5 << bf16 rounding. Saves ~15 VALU ops vs libm tanhf.
__device__ __forceinline__ float ftanh(float v) {
  float x = fminf(fmaxf(v, -10.f), 10.f);
  float e = __expf(2.f * x);
  return (e - 1.f) / (e + 1.f);
}

// Swizzled LDS byte address for A-tiles: row-major [rows][256] bf16 (512 B/row),
// 16B chunks XORed by (row&7) (T2) to kill 512B-stride bank conflicts.
__device__ __forceinline__ int lds_addr(int row, int chunk) {
  return row * 512 + ((chunk ^ (row & 7)) << 4);
}

__device__ __forceinline__ void load_bfrag(const uint16_t* __restrict__ Wbf,
                                           int Cw, int l15, int l4, bf16x8 bf[2][8]) {
#pragma unroll
  for (int cf = 0; cf < 2; ++cf) {
    const uint16_t* bp = Wbf + (Cw + cf * 16 + l15) * 256 + l4 * 8;
#pragma unroll
    for (int s = 0; s < 8; ++s)
      bf[cf][s] = *reinterpret_cast<const bf16x8*>(bp + s * 32);
  }
}

__device__ __forceinline__ void gemm_lds(const uint8_t* base, const bf16x8 bfrag[2][8],
                                         int Rw, int Cw, int l15, int l4, f32x4 acc[2][2]) {
#pragma unroll
  for (int s = 0; s < 8; ++s) {
    bf16x8 a0 = *reinterpret_cast<const bf16x8*>(&base[lds_addr(Rw + l15,      s * 4 + l4)]);
    bf16x8 a1 = *reinterpret_cast<const bf16x8*>(&base[lds_addr(Rw + 16 + l15, s * 4 + l4)]);
    acc[0][0] = MFMA(a0, bfrag[0][s], acc[0][0], 0, 0, 0);
    acc[0][1] = MFMA(a0, bfrag[1][s], acc[0][1], 0, 0, 0);
    acc[1][0] = MFMA(a1, bfrag[0][s], acc[1][0], 0, 0, 0);
    acc[1][1] = MFMA(a1, bfrag[1][s], acc[1][1], 0, 0, 0);
  }
}

// ---- fused 2-level kernel, 32 KiB LDS (occupancy: ~3 blocks/CU) ----
// Block b0: 256 inputs -> 128 L1 rows (2 tiles) -> 64 L2 rows.
// All 8 A-chunks/thread loaded to regs up front (max MLP); tile0 written to
// LDS immediately, tile1 written after GEMM1-t0 reads finish (same 32KB).
// Mid then OutS overlay the same buffer behind barriers.
template<bool LEAF>
__global__ __launch_bounds__(512, 2)
void fused2_kernel(const uint16_t* __restrict__ X,
                   const int* __restrict__ pos_idx, const int* __restrict__ wrd_idx,
                   const uint16_t* __restrict__ pos_bf, const uint16_t* __restrict__ wrd_bf,
                   uint16_t* __restrict__ Y, const uint16_t* __restrict__ Wbf,
                   const float* __restrict__ Wnon, const float* __restrict__ bias,
                   const int* __restrict__ nidx, int off1, int off2)
{
  __shared__ uint8_t Abuf[32768];
  const int tid = threadIdx.x, w = tid >> 6, lane = tid & 63;
  const int Rw = (w >> 2) * 32, Cw = (w & 3) * 32;
  const int l15 = lane & 15, l4 = lane >> 4;
  const int b0 = blockIdx.x;

  // ---- issue ALL 8 gather/stream loads up front ----
  int4 stg[8];
#pragma unroll
  for (int k = 0; k < 8; ++k) {
    const int cg = tid + k * 512;            // global chunk id [0,4096)
    const int t = cg >> 11;                  // tile 0/1
    const int ct = cg & 2047;                // chunk within tile
    const int arow = ct >> 5;                // A-row [0,64)
    const int c = (ct & 31) ^ (arow & 7);    // logical 16B chunk (pre-swizzled source)
    if (LEAF) {
      // A-row layout: [pos(leafL)|wrd(leafL)|pos(leafR)|wrd(leafR)], 8 chunks each
      const int seg = c >> 3;
      const int leaf = 2 * (b0 * 128 + t * 64 + arow) + (seg >> 1);
      const int idx = (seg & 1) ? wrd_idx[leaf] : pos_idx[leaf];
      const uint16_t* tab = (seg & 1) ? wrd_bf : pos_bf;
      stg[k] = *reinterpret_cast<const int4*>(tab + (size_t)idx * 64 + (c & 7) * 8);
    } else {
      stg[k] = *reinterpret_cast<const int4*>(
          reinterpret_cast<const uint8_t*>(X) +
          (((size_t)(b0 * 128 + t * 64 + arow)) << 9) + (c << 4));
    }
  }

  bf16x8 bfrag[2][8];
  load_bfrag(Wbf, Cw, l15, l4, bfrag);

  // ---- tile0 -> LDS ----
#pragma unroll
  for (int k = 0; k < 4; ++k)
    *reinterpret_cast<int4*>(&Abuf[(tid + k * 512) << 4]) = stg[k];
  __syncthreads();

  // ---- GEMM1 tile 0 ----
  f32x4 acc0[2][2] = {}, acc1[2][2] = {};
  gemm_lds(Abuf, bfrag, Rw, Cw, l15, l4, acc0);
  __syncthreads();                           // tile0 reads done

  // ---- tile1 -> LDS (same space) ----
#pragma unroll
  for (int k = 4; k < 8; ++k)
    *reinterpret_cast<int4*>(&Abuf[(tid + (k - 4) * 512) << 4]) = stg[k];
  __syncthreads();

  // ---- GEMM1 tile 1 ----
  gemm_lds(Abuf, bfrag, Rw, Cw, l15, l4, acc1);
  __syncthreads();                           // tile1 reads done; Mid may overlay

  // ---- epilogue tiles 0,1 -> Mid (= Abuf, next-level A layout, swizzled) ----
#pragma unroll
  for (int t = 0; t < 2; ++t) {
    const f32x4 (*acc)[2] = t ? acc1 : acc0;
#pragma unroll
    for (int rf = 0; rf < 2; ++rf) {
#pragma unroll
      for (int reg = 0; reg < 4; ++reg) {
        const int r1 = t * 64 + Rw + rf * 16 + l4 * 4 + reg;  // [0,128)
        const int ni = nidx[off1 + b0 * 128 + r1];
#pragma unroll
        for (int cf = 0; cf < 2; ++cf) {
          const int col = Cw + cf * 16 + l15;
          const float v = acc[rf][cf][reg] + bias[col] + Wnon[ni * 128 + col];
          const int r2 = r1 >> 1;
          const int colA = (r1 & 1) * 128 + col;
          *reinterpret_cast<uint16_t*>(
              &Abuf[r2 * 512 + (((colA >> 3) ^ (r2 & 7)) << 4) + (colA & 7) * 2]) =
              f2bf(ftanh(v));
        }
      }
    }
  }
  __syncthreads();                           // Mid complete

  // ---- GEMM2 from Mid; epilogue -> OutS (= Abuf[0:16K), after barrier) ----
  {
    f32x4 acc[2][2] = {};
    gemm_lds(Abuf, bfrag, Rw, Cw, l15, l4, acc);
    __syncthreads();                         // Mid reads done; OutS may overlay
#pragma unroll
    for (int rf = 0; rf < 2; ++rf) {
#pragma unroll
      for (int reg = 0; reg < 4; ++reg) {
        const int row = Rw + rf * 16 + l4 * 4 + reg;
        const int ni = nidx[off2 + b0 * 64 + row];
#pragma unroll
        for (int cf = 0; cf < 2; ++cf) {
          const int col = Cw + cf * 16 + l15;
          const float v = acc[rf][cf][reg] + bias[col] + Wnon[ni * 128 + col];
          const int colb = col * 2;
          *reinterpret_cast<uint16_t*>(
              &Abuf[row * 256 + (((colb >> 4) ^ (row & 7)) << 4) + (colb & 15)]) =
              f2bf(ftanh(v));
        }
      }
    }
  }
  __syncthreads();                           // OutS complete

  // ---- coalesced store: 512 threads x 32B contiguous (full lines, no RFO) ----
  {
    const int row = tid >> 3, c2 = (tid & 7) * 2;
    int4 v0 = *reinterpret_cast<const int4*>(&Abuf[row * 256 + ((c2       ^ (row & 7)) << 4)]);
    int4 v1 = *reinterpret_cast<const int4*>(&Abuf[row * 256 + (((c2 + 1) ^ (row & 7)) << 4)]);
    uint8_t* dst = reinterpret_cast<uint8_t*>(Y) + ((size_t)b0 * 64 + row) * 256 + c2 * 16;
    *reinterpret_cast<int4*>(dst) = v0;
    *reinterpret_cast<int4*>(dst + 16) = v1;
  }
}

// ---- tail: levels n=256..1 in ONE block ----
__global__ __launch_bounds__(512, 1)
void tail_kernel(const uint16_t* __restrict__ X, const uint16_t* __restrict__ Wbf,
                 const float* __restrict__ Wnon, const float* __restrict__ bias,
                 const int* __restrict__ nidx, int base_off, float* __restrict__ out)
{
  __shared__ uint8_t P[98304];   // buf0 @0 (64KB), buf1 @65536 (32KB)
  const int tid = threadIdx.x, w = tid >> 6, lane = tid & 63;
  const int Rw = (w >> 2) * 32, Cw = (w & 3) * 32;
  const int l15 = lane & 15, l4 = lane >> 4;

  bf16x8 bfrag[2][8];
  load_bfrag(Wbf, Cw, l15, l4, bfrag);

  int off = base_off;

  // ---- n=256 from global ----
  for (int t = 0; t < 4; ++t) {
    f32x4 acc[2][2] = {};
    const uint16_t* Xa = X + (size_t)(t * 64 + Rw + l15) * 256 + l4 * 8;
    const uint16_t* Xb = Xa + 16 * 256;
#pragma unroll
    for (int s = 0; s < 8; ++s) {
      bf16x8 a0 = *reinterpret_cast<const bf16x8*>(Xa + s * 32);
      bf16x8 a1 = *reinterpret_cast<const bf16x8*>(Xb + s * 32);
      acc[0][0] = MFMA(a0, bfrag[0][s], acc[0][0], 0, 0, 0);
      acc[0][1] = MFMA(a0, bfrag[1][s], acc[0][1], 0, 0, 0);
      acc[1][0] = MFMA(a1, bfrag[0][s], acc[1][0], 0, 0, 0);
      acc[1][1] = MFMA(a1, bfrag[1][s], acc[1][1], 0, 0, 0);
    }
#pragma unroll
    for (int rf = 0; rf < 2; ++rf) {
#pragma unroll
      for (int reg = 0; reg < 4; ++reg) {
        const int r1 = t * 64 + Rw + rf * 16 + l4 * 4 + reg;
        const int ni = nidx[off + r1];
#pragma unroll
        for (int cf = 0; cf < 2; ++cf) {
          const int col = Cw + cf * 16 + l15;
          const float v = acc[rf][cf][reg] + bias[col] + Wnon[ni * 128 + col];
          const int r2 = r1 >> 1;
          const int colA = (r1 & 1) * 128 + col;
          *reinterpret_cast<uint16_t*>(
              &P[r2 * 512 + (((colA >> 3) ^ (r2 & 7)) << 4) + (colA & 7) * 2]) =
              f2bf(ftanh(v));
        }
      }
    }
  }
  off += 256;
  __syncthreads();

  int cur = 0;                                  // A for n=128 lives in buf0
  for (int n = 128; n >= 1; n >>= 1) {
    const uint8_t* Pin = P + (cur ? 65536 : 0);
    uint8_t* Pout = P + (cur ? 0 : 65536);
    const int ntiles = (n + 63) >> 6;
    for (int t = 0; t < ntiles; ++t) {
      f32x4 acc[2][2] = {};
#pragma unroll
      for (int s = 0; s < 8; ++s) {
        bf16x8 a0 = *reinterpret_cast<const bf16x8*>(&Pin[lds_addr(t * 64 + Rw + l15,      s * 4 + l4)]);
        bf16x8 a1 = *reinterpret_cast<const bf16x8*>(&Pin[lds_addr(t * 64 + Rw + 16 + l15, s * 4 + l4)]);
        acc[0][0] = MFMA(a0, bfrag[0][s], acc[0][0], 0, 0, 0);
        acc[0][1] = MFMA(a0, bfrag[1][s], acc[0][1], 0, 0, 0);
        acc[1][0] = MFMA(a1, bfrag[0][s], acc[1][0], 0, 0, 0);
        acc[1][1] = MFMA(a1, bfrag[1][s], acc[1][1], 0, 0, 0);
      }
#pragma unroll
      for (int rf = 0; rf < 2; ++rf) {
#pragma unroll
        for (int reg = 0; reg < 4; ++reg) {
          const int rl = t * 64 + Rw + rf * 16 + l4 * 4 + reg;
          const int rcl = rl < n ? rl : n - 1;          // clamp idx for garbage rows
          const int ni = nidx[off + rcl];
#pragma unroll
          for (int cf = 0; cf < 2; ++cf) {
            const int col = Cw + cf * 16 + l15;
            const float v = acc[rf][cf][reg] + bias[col] + Wnon[ni * 128 + col];
            const float y = ftanh(v);
            if (n == 1) {
              if (rl == 0) out[col] = y;
            } else if (rl < n) {
              const int r2 = rl >> 1;
              const int colA = (rl & 1) * 128 + col;
              *reinterpret_cast<uint16_t*>(
                  &Pout[r2 * 512 + (((colA >> 3) ^ (r2 & 7)) << 4) + (colA & 7) * 2]) =
                  f2bf(y);
            }
          }
        }
      }
    }
    off += n;
    cur ^= 1;
    __syncthreads();
  }
}

// ---- prep: convert Wc_w / Wpos / Wwrd fp32 -> bf16 (layouts unchanged) ----
__global__ void prep_all(const float* __restrict__ Wc_w, const float* __restrict__ Wpos,
                         const float* __restrict__ Wwrd, uint16_t* __restrict__ wc_bf,
                         uint16_t* __restrict__ pos_bf, uint16_t* __restrict__ wrd_bf)
{
  int g = blockIdx.x * 256 + threadIdx.x;       // one 8-float group each
  const float* src; uint16_t* dst; int idx;
  if (g < 4096)      { src = Wc_w; dst = wc_bf;  idx = g; }
  else if (g < 4608) { src = Wpos; dst = pos_bf; idx = g - 4096; }
  else               { src = Wwrd; dst = wrd_bf; idx = g - 4608; }
  float4 f0 = reinterpret_cast<const float4*>(src)[idx * 2];
  float4 f1 = reinterpret_cast<const float4*>(src)[idx * 2 + 1];
  union { int4 v; uint16_t u[8]; } pk;
  pk.u[0] = f2bf(f0.x); pk.u[1] = f2bf(f0.y); pk.u[2] = f2bf(f0.z); pk.u[3] = f2bf(f0.w);
  pk.u[4] = f2bf(f1.x); pk.u[5] = f2bf(f1.y); pk.u[6] = f2bf(f1.z); pk.u[7] = f2bf(f1.w);
  reinterpret_cast<int4*>(dst)[idx] = pk.v;
}

extern "C" void kernel_launch(void* const* d_in, const int* in_sizes, int n_in,
                              void* d_out, int out_size, void* d_ws, size_t ws_size,
                              hipStream_t stream)
{
  const int*   pos_idx = (const int*)d_in[0];
  const int*   wrd_idx = (const int*)d_in[1];
  const int*   non_idx = (const int*)d_in[2];
  const float* Wwrd    = (const float*)d_in[3];
  const float* Wpos    = (const float*)d_in[4];
  const float* Wnon    = (const float*)d_in[5];
  const float* Wc_w    = (const float*)d_in[6];
  const float* Wc_b    = (const float*)d_in[7];
  float* out = (float*)d_out;

  uint8_t* ws = (uint8_t*)d_ws;
  uint16_t* Wbf    = (uint16_t*)ws;                               // 64 KiB
  uint16_t* pos_bf = (uint16_t*)(ws + 65536);                     // 8 KiB
  uint16_t* wrd_bf = (uint16_t*)(ws + 65536 + 8192);              // 12.8 MB
  uint16_t* S1     = (uint16_t*)(ws + 12873728);                  // 33.6 MB (131072x128 bf16)
  uint16_t* S2     = (uint16_t*)(ws + 46428160);                  // 8.4 MB  (32768x128 bf16)

  prep_all<<<3143, 256, 0, stream>>>(Wc_w, Wpos, Wwrd, Wbf, pos_bf, wrd_bf);

  // Level offsets into non_idx: L1=0(262144), L2=262144(131072), L3=393216(65536),
  // L4=458752(32768), L5=491520(16384), L6=507904(8192), L7=516096(4096),
  // L8=520192(2048), L9=522240(1024), L10=523264(512), tail from 523776(256..1).

  // leaf + L1 + L2 fused: gather -> 262144 -> 131072 rows
  fused2_kernel<true><<<2048, 512, 0, stream>>>(nullptr, pos_idx, wrd_idx, pos_bf, wrd_bf,
                                                S1, Wbf, Wnon, Wc_b, non_idx, 0, 262144);
  // L3+L4: 131072 -> 65536 -> 32768
  fused2_kernel<false><<<512, 512, 0, stream>>>(S1, nullptr, nullptr, nullptr, nullptr,
                                                S2, Wbf, Wnon, Wc_b, non_idx, 393216, 458752);
  // L5+L6: 32768 -> 16384 -> 8192
  fused2_kernel<false><<<128, 512, 0, stream>>>(S2, nullptr, nullptr, nullptr, nullptr,
                                                S1, Wbf, Wnon, Wc_b, non_idx, 491520, 507904);
  // L7+L8: 8192 -> 4096 -> 2048
  fused2_kernel<false><<<32, 512, 0, stream>>>(S1, nullptr, nullptr, nullptr, nullptr,
                                               S2, Wbf, Wnon, Wc_b, non_idx, 516096, 520192);
  // L9+L10: 2048 -> 1024 -> 512
  fused2_kernel<false><<<8, 512, 0, stream>>>(S2, nullptr, nullptr, nullptr, nullptr,
                                              S1, Wbf, Wnon, Wc_b, non_idx, 522240, 523264);
  // tail: 256..1 (reads 512 rows in S1)
  tail_kernel<<<1, 512, 0, stream>>>(S1, Wbf, Wnon, Wc_b, non_idx, 523776, out);
}

// Round 6
// 227.343 us; speedup vs baseline: 1.6383x; 1.1355x over previous
//
#include <hip/hip_runtime.h>
#include <stdint.h>

typedef __attribute__((ext_vector_type(8))) __bf16 bf16x8;
typedef __attribute__((ext_vector_type(4))) float f32x4;

#define MFMA __builtin_amdgcn_mfma_f32_16x16x32_bf16

// fp32 -> bf16 round-to-nearest-even
__device__ __forceinline__ uint16_t f2bf(float f) {
  uint32_t u = __float_as_uint(f);
  return (uint16_t)((u + 0x7fffu + ((u >> 16) & 1u)) >> 16);
}

// fast tanh: clamp then (e^2x-1)/(e^2x+1); rel err ~1e-5 << bf16 rounding
__device__ __forceinline__ float ftanh(float v) {
  float x = fminf(fmaxf(v, -10.f), 10.f);
  float e = __expf(2.f * x);
  return (e - 1.f) / (e + 1.f);
}

// async 16B global->LDS (zero staging VGPRs)
__device__ __forceinline__ void gl2lds16(const void* g, void* l) {
  __builtin_amdgcn_global_load_lds(
      (const __attribute__((address_space(1))) unsigned int*)g,
      (__attribute__((address_space(3))) unsigned int*)l, 16, 0, 0);
}

// Swizzled LDS byte address for A-tiles: row-major [64][256] bf16 (512 B/row),
// 16B chunks XORed by (row&7) (T2). Staging writes LINEAR; the XOR is applied
// to the per-lane global SOURCE address (involution on both sides).
__device__ __forceinline__ int lds_addr(int row, int chunk) {
  return row * 512 + ((chunk ^ (row & 7)) << 4);
}

__device__ __forceinline__ void load_bfrag(const uint16_t* __restrict__ Wbf,
                                           int Cw, int l15, int l4, bf16x8 bf[2][8]) {
#pragma unroll
  for (int cf = 0; cf < 2; ++cf) {
    const uint16_t* bp = Wbf + (Cw + cf * 16 + l15) * 256 + l4 * 8;
#pragma unroll
    for (int s = 0; s < 8; ++s)
      bf[cf][s] = *reinterpret_cast<const bf16x8*>(bp + s * 32);
  }
}

__device__ __forceinline__ void gemm_lds(const uint8_t* base, const bf16x8 bfrag[2][8],
                                         int Rw, int Cw, int l15, int l4, f32x4 acc[2][2]) {
#pragma unroll
  for (int s = 0; s < 8; ++s) {
    bf16x8 a0 = *reinterpret_cast<const bf16x8*>(&base[lds_addr(Rw + l15,      s * 4 + l4)]);
    bf16x8 a1 = *reinterpret_cast<const bf16x8*>(&base[lds_addr(Rw + 16 + l15, s * 4 + l4)]);
    acc[0][0] = MFMA(a0, bfrag[0][s], acc[0][0], 0, 0, 0);
    acc[0][1] = MFMA(a0, bfrag[1][s], acc[0][1], 0, 0, 0);
    acc[1][0] = MFMA(a1, bfrag[0][s], acc[1][0], 0, 0, 0);
    acc[1][1] = MFMA(a1, bfrag[1][s], acc[1][1], 0, 0, 0);
  }
}

// ---- fused 2-level kernel, 32 KiB LDS, global_load_lds staging ----
// Block b0: 256 inputs -> 128 L1 rows (2 tiles through the same 32KB) -> 64 L2 rows.
// L1 outputs held as packed bf16 in regs; Mid and OutS overlay Abuf behind barriers.
template<bool LEAF>
__global__ __launch_bounds__(512, 4)
void fused2_kernel(const uint16_t* __restrict__ X,
                   const int* __restrict__ pos_idx, const int* __restrict__ wrd_idx,
                   const uint16_t* __restrict__ pos_bf, const uint16_t* __restrict__ wrd_bf,
                   uint16_t* __restrict__ Y, const uint16_t* __restrict__ Wbf,
                   const float* __restrict__ Wnon, const float* __restrict__ bias,
                   const int* __restrict__ nidx, int off1, int off2)
{
  __shared__ uint8_t Abuf[32768];
  const int tid = threadIdx.x, w = tid >> 6, lane = tid & 63;
  const int Rw = (w >> 2) * 32, Cw = (w & 3) * 32;
  const int l15 = lane & 15, l4 = lane >> 4;
  const int b0 = blockIdx.x;

  bf16x8 bfrag[2][8];
  load_bfrag(Wbf, Cw, l15, l4, bfrag);

  uint32_t pk[2][2][4];                      // packed L1 outputs (cf0 | cf1<<16)

#pragma unroll
  for (int t = 0; t < 2; ++t) {
    // ---- stage tile t: 2048 x 16B chunks via global_load_lds ----
#pragma unroll
    for (int k = 0; k < 4; ++k) {
      const int ct = tid + k * 512;          // linear LDS chunk [0,2048)
      const int arow = ct >> 5;
      const int c = (ct & 31) ^ (arow & 7);  // pre-swizzled logical chunk
      const void* src;
      if (LEAF) {
        const int seg = c >> 3;              // [posL|wrdL|posR|wrdR]
        const int leaf = 2 * (b0 * 128 + t * 64 + arow) + (seg >> 1);
        const int idx = (seg & 1) ? wrd_idx[leaf] : pos_idx[leaf];
        const uint16_t* tab = (seg & 1) ? wrd_bf : pos_bf;
        src = tab + (size_t)idx * 64 + (c & 7) * 8;
      } else {
        src = X + ((size_t)(b0 * 128 + t * 64 + arow)) * 256 + c * 8;
      }
      gl2lds16(src, &Abuf[ct << 4]);
    }
    __syncthreads();                         // staged (syncthreads drains vmcnt)

    // ---- GEMM1 tile t + epilogue to packed regs (no LDS writes) ----
    f32x4 acc[2][2] = {};
    gemm_lds(Abuf, bfrag, Rw, Cw, l15, l4, acc);
#pragma unroll
    for (int rf = 0; rf < 2; ++rf) {
#pragma unroll
      for (int reg = 0; reg < 4; ++reg) {
        const int r1 = t * 64 + Rw + rf * 16 + l4 * 4 + reg;
        const int ni = nidx[off1 + b0 * 128 + r1];
        const int c0 = Cw + l15, c1 = Cw + 16 + l15;
        const float v0 = acc[0][rf == 0 ? 0 : 0][0];  // placeholder (overwritten below)
        float va = acc[rf][0][reg] + bias[c0] + Wnon[ni * 128 + c0];
        float vb = acc[rf][1][reg] + bias[c1] + Wnon[ni * 128 + c1];
        (void)v0;
        pk[t][rf][reg] = (uint32_t)f2bf(ftanh(va)) | ((uint32_t)f2bf(ftanh(vb)) << 16);
      }
    }
    __syncthreads();                         // tile t LDS reads done; Abuf reusable
  }

  // ---- write Mid (= Abuf, next-level A layout, swizzled) from packed regs ----
#pragma unroll
  for (int t = 0; t < 2; ++t) {
#pragma unroll
    for (int rf = 0; rf < 2; ++rf) {
#pragma unroll
      for (int reg = 0; reg < 4; ++reg) {
        const int r1 = t * 64 + Rw + rf * 16 + l4 * 4 + reg;
        const int r2 = r1 >> 1;
        const uint32_t p = pk[t][rf][reg];
#pragma unroll
        for (int cf = 0; cf < 2; ++cf) {
          const int col = Cw + cf * 16 + l15;
          const int colA = (r1 & 1) * 128 + col;
          *reinterpret_cast<uint16_t*>(
              &Abuf[r2 * 512 + (((colA >> 3) ^ (r2 & 7)) << 4) + (colA & 7) * 2]) =
              (uint16_t)(cf ? (p >> 16) : (p & 0xffff));
        }
      }
    }
  }
  __syncthreads();                           // Mid complete

  // ---- GEMM2 from Mid; epilogue -> OutS (= Abuf[0:16K), after barrier) ----
  {
    f32x4 acc[2][2] = {};
    gemm_lds(Abuf, bfrag, Rw, Cw, l15, l4, acc);
    __syncthreads();                         // Mid reads done; OutS may overlay
#pragma unroll
    for (int rf = 0; rf < 2; ++rf) {
#pragma unroll
      for (int reg = 0; reg < 4; ++reg) {
        const int row = Rw + rf * 16 + l4 * 4 + reg;
        const int ni = nidx[off2 + b0 * 64 + row];
#pragma unroll
        for (int cf = 0; cf < 2; ++cf) {
          const int col = Cw + cf * 16 + l15;
          const float v = acc[rf][cf][reg] + bias[col] + Wnon[ni * 128 + col];
          const int colb = col * 2;
          *reinterpret_cast<uint16_t*>(
              &Abuf[row * 256 + (((colb >> 4) ^ (row & 7)) << 4) + (colb & 15)]) =
              f2bf(ftanh(v));
        }
      }
    }
  }
  __syncthreads();                           // OutS complete

  // ---- coalesced store: 512 threads x 32B contiguous ----
  {
    const int row = tid >> 3, c2 = (tid & 7) * 2;
    int4 v0 = *reinterpret_cast<const int4*>(&Abuf[row * 256 + ((c2       ^ (row & 7)) << 4)]);
    int4 v1 = *reinterpret_cast<const int4*>(&Abuf[row * 256 + (((c2 + 1) ^ (row & 7)) << 4)]);
    uint8_t* dst = reinterpret_cast<uint8_t*>(Y) + ((size_t)b0 * 64 + row) * 256 + c2 * 16;
    *reinterpret_cast<int4*>(dst) = v0;
    *reinterpret_cast<int4*>(dst + 16) = v1;
  }
}

// ---- small level: 1 wave / 16-row tile, no LDS, no barriers ----
__global__ __launch_bounds__(64, 4)
void small_kernel(const uint16_t* __restrict__ X, uint16_t* __restrict__ Y,
                  const uint16_t* __restrict__ Wbf, const float* __restrict__ Wnon,
                  const float* __restrict__ bias, const int* __restrict__ nidx,
                  int off)
{
  const int lane = threadIdx.x, l15 = lane & 15, l4 = lane >> 4;
  const int r0 = blockIdx.x * 16;
  f32x4 acc[8] = {};
  const uint16_t* Xr = X + (size_t)(r0 + l15) * 256 + l4 * 8;
#pragma unroll
  for (int s = 0; s < 8; ++s) {
    bf16x8 a = *reinterpret_cast<const bf16x8*>(Xr + s * 32);
#pragma unroll
    for (int cf = 0; cf < 8; ++cf) {
      bf16x8 b = *reinterpret_cast<const bf16x8*>(Wbf + (cf * 16 + l15) * 256 + l4 * 8 + s * 32);
      acc[cf] = MFMA(a, b, acc[cf], 0, 0, 0);
    }
  }
#pragma unroll
  for (int reg = 0; reg < 4; ++reg) {
    const int row = r0 + l4 * 4 + reg;
    const int ni = nidx[off + row];
#pragma unroll
    for (int cf = 0; cf < 8; ++cf) {
      const int col = cf * 16 + l15;
      const float v = acc[cf][reg] + bias[col] + Wnon[ni * 128 + col];
      Y[(size_t)row * 128 + col] = f2bf(ftanh(v));
    }
  }
}

// ---- tail: levels n=256..1 in ONE block ----
__global__ __launch_bounds__(512, 1)
void tail_kernel(const uint16_t* __restrict__ X, const uint16_t* __restrict__ Wbf,
                 const float* __restrict__ Wnon, const float* __restrict__ bias,
                 const int* __restrict__ nidx, int base_off, float* __restrict__ out)
{
  __shared__ uint8_t P[98304];   // buf0 @0 (64KB), buf1 @65536 (32KB)
  const int tid = threadIdx.x, w = tid >> 6, lane = tid & 63;
  const int Rw = (w >> 2) * 32, Cw = (w & 3) * 32;
  const int l15 = lane & 15, l4 = lane >> 4;

  bf16x8 bfrag[2][8];
  load_bfrag(Wbf, Cw, l15, l4, bfrag);

  int off = base_off;

  // ---- n=256 from global (512 input rows) ----
  for (int t = 0; t < 4; ++t) {
    f32x4 acc[2][2] = {};
    const uint16_t* Xa = X + (size_t)(t * 64 + Rw + l15) * 256 + l4 * 8;
    const uint16_t* Xb = Xa + 16 * 256;
#pragma unroll
    for (int s = 0; s < 8; ++s) {
      bf16x8 a0 = *reinterpret_cast<const bf16x8*>(Xa + s * 32);
      bf16x8 a1 = *reinterpret_cast<const bf16x8*>(Xb + s * 32);
      acc[0][0] = MFMA(a0, bfrag[0][s], acc[0][0], 0, 0, 0);
      acc[0][1] = MFMA(a0, bfrag[1][s], acc[0][1], 0, 0, 0);
      acc[1][0] = MFMA(a1, bfrag[0][s], acc[1][0], 0, 0, 0);
      acc[1][1] = MFMA(a1, bfrag[1][s], acc[1][1], 0, 0, 0);
    }
#pragma unroll
    for (int rf = 0; rf < 2; ++rf) {
#pragma unroll
      for (int reg = 0; reg < 4; ++reg) {
        const int r1 = t * 64 + Rw + rf * 16 + l4 * 4 + reg;
        const int ni = nidx[off + r1];
#pragma unroll
        for (int cf = 0; cf < 2; ++cf) {
          const int col = Cw + cf * 16 + l15;
          const float v = acc[rf][cf][reg] + bias[col] + Wnon[ni * 128 + col];
          const int r2 = r1 >> 1;
          const int colA = (r1 & 1) * 128 + col;
          *reinterpret_cast<uint16_t*>(
              &P[r2 * 512 + (((colA >> 3) ^ (r2 & 7)) << 4) + (colA & 7) * 2]) =
              f2bf(ftanh(v));
        }
      }
    }
  }
  off += 256;
  __syncthreads();

  int cur = 0;
  for (int n = 128; n >= 1; n >>= 1) {
    const uint8_t* Pin = P + (cur ? 65536 : 0);
    uint8_t* Pout = P + (cur ? 0 : 65536);
    const int ntiles = (n + 63) >> 6;
    for (int t = 0; t < ntiles; ++t) {
      f32x4 acc[2][2] = {};
#pragma unroll
      for (int s = 0; s < 8; ++s) {
        bf16x8 a0 = *reinterpret_cast<const bf16x8*>(&Pin[lds_addr(t * 64 + Rw + l15,      s * 4 + l4)]);
        bf16x8 a1 = *reinterpret_cast<const bf16x8*>(&Pin[lds_addr(t * 64 + Rw + 16 + l15, s * 4 + l4)]);
        acc[0][0] = MFMA(a0, bfrag[0][s], acc[0][0], 0, 0, 0);
        acc[0][1] = MFMA(a0, bfrag[1][s], acc[0][1], 0, 0, 0);
        acc[1][0] = MFMA(a1, bfrag[0][s], acc[1][0], 0, 0, 0);
        acc[1][1] = MFMA(a1, bfrag[1][s], acc[1][1], 0, 0, 0);
      }
#pragma unroll
      for (int rf = 0; rf < 2; ++rf) {
#pragma unroll
        for (int reg = 0; reg < 4; ++reg) {
          const int rl = t * 64 + Rw + rf * 16 + l4 * 4 + reg;
          const int rcl = rl < n ? rl : n - 1;
          const int ni = nidx[off + rcl];
#pragma unroll
          for (int cf = 0; cf < 2; ++cf) {
            const int col = Cw + cf * 16 + l15;
            const float v = acc[rf][cf][reg] + bias[col] + Wnon[ni * 128 + col];
            const float y = ftanh(v);
            if (n == 1) {
              if (rl == 0) out[col] = y;
            } else if (rl < n) {
              const int r2 = rl >> 1;
              const int colA = (rl & 1) * 128 + col;
              *reinterpret_cast<uint16_t*>(
                  &Pout[r2 * 512 + (((colA >> 3) ^ (r2 & 7)) << 4) + (colA & 7) * 2]) =
                  f2bf(y);
            }
          }
        }
      }
    }
    off += n;
    cur ^= 1;
    __syncthreads();
  }
}

// ---- prep: convert Wc_w / Wpos / Wwrd fp32 -> bf16 ----
__global__ void prep_all(const float* __restrict__ Wc_w, const float* __restrict__ Wpos,
                         const float* __restrict__ Wwrd, uint16_t* __restrict__ wc_bf,
                         uint16_t* __restrict__ pos_bf, uint16_t* __restrict__ wrd_bf)
{
  int g = blockIdx.x * 256 + threadIdx.x;
  const float* src; uint16_t* dst; int idx;
  if (g < 4096)      { src = Wc_w; dst = wc_bf;  idx = g; }
  else if (g < 4608) { src = Wpos; dst = pos_bf; idx = g - 4096; }
  else               { src = Wwrd; dst = wrd_bf; idx = g - 4608; }
  float4 f0 = reinterpret_cast<const float4*>(src)[idx * 2];
  float4 f1 = reinterpret_cast<const float4*>(src)[idx * 2 + 1];
  union { int4 v; uint16_t u[8]; } pkv;
  pkv.u[0] = f2bf(f0.x); pkv.u[1] = f2bf(f0.y); pkv.u[2] = f2bf(f0.z); pkv.u[3] = f2bf(f0.w);
  pkv.u[4] = f2bf(f1.x); pkv.u[5] = f2bf(f1.y); pkv.u[6] = f2bf(f1.z); pkv.u[7] = f2bf(f1.w);
  reinterpret_cast<int4*>(dst)[idx] = pkv.v;
}

extern "C" void kernel_launch(void* const* d_in, const int* in_sizes, int n_in,
                              void* d_out, int out_size, void* d_ws, size_t ws_size,
                              hipStream_t stream)
{
  const int*   pos_idx = (const int*)d_in[0];
  const int*   wrd_idx = (const int*)d_in[1];
  const int*   non_idx = (const int*)d_in[2];
  const float* Wwrd    = (const float*)d_in[3];
  const float* Wpos    = (const float*)d_in[4];
  const float* Wnon    = (const float*)d_in[5];
  const float* Wc_w    = (const float*)d_in[6];
  const float* Wc_b    = (const float*)d_in[7];
  float* out = (float*)d_out;

  uint8_t* ws = (uint8_t*)d_ws;
  uint16_t* Wbf    = (uint16_t*)ws;                               // 64 KiB
  uint16_t* pos_bf = (uint16_t*)(ws + 65536);                     // 8 KiB
  uint16_t* wrd_bf = (uint16_t*)(ws + 65536 + 8192);              // 12.8 MB
  uint16_t* S1     = (uint16_t*)(ws + 12873728);                  // 33.6 MB
  uint16_t* S2     = (uint16_t*)(ws + 46428160);                  // 8.4 MB

  prep_all<<<3143, 256, 0, stream>>>(Wc_w, Wpos, Wwrd, Wbf, pos_bf, wrd_bf);

  // Level offsets: L1=0(262144), L2=262144(131072), L3=393216(65536),
  // L4=458752(32768), L5=491520(16384), L6=507904(8192), L7=516096(4096),
  // L8=520192(2048), L9=522240(1024), L10=523264(512), tail from 523776.

  fused2_kernel<true><<<2048, 512, 0, stream>>>(nullptr, pos_idx, wrd_idx, pos_bf, wrd_bf,
                                                S1, Wbf, Wnon, Wc_b, non_idx, 0, 262144);
  fused2_kernel<false><<<512, 512, 0, stream>>>(S1, nullptr, nullptr, nullptr, nullptr,
                                                S2, Wbf, Wnon, Wc_b, non_idx, 393216, 458752);
  fused2_kernel<false><<<128, 512, 0, stream>>>(S2, nullptr, nullptr, nullptr, nullptr,
                                                S1, Wbf, Wnon, Wc_b, non_idx, 491520, 507904);
  fused2_kernel<false><<<32, 512, 0, stream>>>(S1, nullptr, nullptr, nullptr, nullptr,
                                               S2, Wbf, Wnon, Wc_b, non_idx, 516096, 520192);
  // L9 (n=1024): S2 (2048 rows) -> S1 ; L10 (n=512): S1 -> S2
  small_kernel<<<64, 64, 0, stream>>>(S2, S1, Wbf, Wnon, Wc_b, non_idx, 522240);
  small_kernel<<<32, 64, 0, stream>>>(S1, S2, Wbf, Wnon, Wc_b, non_idx, 523264);
  // tail: 256..1 (reads 512 rows in S2)
  tail_kernel<<<1, 512, 0, stream>>>(S2, Wbf, Wnon, Wc_b, non_idx, 523776, out);
}

// Round 7
// 186.802 us; speedup vs baseline: 1.9938x; 1.2170x over previous
//
#include <hip/hip_runtime.h>
#include <stdint.h>

typedef __attribute__((ext_vector_type(8))) __bf16 bf16x8;
typedef __attribute__((ext_vector_type(4))) float f32x4;

#define MFMA __builtin_amdgcn_mfma_f32_16x16x32_bf16

// fp32 -> bf16 round-to-nearest-even
__device__ __forceinline__ uint16_t f2bf(float f) {
  uint32_t u = __float_as_uint(f);
  return (uint16_t)((u + 0x7fffu + ((u >> 16) & 1u)) >> 16);
}

// fast tanh: clamp then (e^2x-1)/(e^2x+1); rel err ~1e-5 << bf16 rounding
__device__ __forceinline__ float ftanh(float v) {
  float x = fminf(fmaxf(v, -10.f), 10.f);
  float e = __expf(2.f * x);
  return (e - 1.f) / (e + 1.f);
}

// async 16B global->LDS (zero staging VGPRs)
__device__ __forceinline__ void gl2lds16(const void* g, void* l) {
  __builtin_amdgcn_global_load_lds(
      (const __attribute__((address_space(1))) unsigned int*)g,
      (__attribute__((address_space(3))) unsigned int*)l, 16, 0, 0);
}

// Swizzled LDS byte address for A-tiles: row-major [64][256] bf16 (512 B/row),
// 16B chunks XORed by (row&7) (T2). Staging writes LINEAR; the XOR is applied
// to the per-lane global SOURCE address (involution on both sides).
__device__ __forceinline__ int lds_addr(int row, int chunk) {
  return row * 512 + ((chunk ^ (row & 7)) << 4);
}

// ---- 16-cols-per-wave GEMM: wave computes 64 rows x 16 cols from LDS A ----
// bfrag = 8 frags (32 VGPR) -> compiler can keep B resident (the round-6 fix).
__device__ __forceinline__ void gemm16(const uint8_t* base, const bf16x8 bfrag[8],
                                       int l15, int l4, f32x4 acc[4]) {
#pragma unroll
  for (int s = 0; s < 8; ++s) {
#pragma unroll
    for (int rf = 0; rf < 4; ++rf) {
      bf16x8 a = *reinterpret_cast<const bf16x8*>(&base[lds_addr(rf * 16 + l15, s * 4 + l4)]);
      acc[rf] = MFMA(a, bfrag[s], acc[rf], 0, 0, 0);
    }
  }
}

// ---- fused 2-level kernel, 32 KiB LDS, global_load_lds staging ----
// Block b0: 256 inputs -> 128 L1 rows (2 tiles through the same 32KB) -> 64 L2 rows.
// Wave wv owns output cols [wv*16, wv*16+16). L1 outputs packed in regs.
template<bool LEAF>
__global__ __launch_bounds__(512, 4)
void fused2_kernel(const uint16_t* __restrict__ X,
                   const int* __restrict__ pos_idx, const int* __restrict__ wrd_idx,
                   const uint16_t* __restrict__ pos_bf, const uint16_t* __restrict__ wrd_bf,
                   uint16_t* __restrict__ Y, const uint16_t* __restrict__ Wbf,
                   const float* __restrict__ wnp,
                   const int* __restrict__ nidx, int off1, int off2)
{
  __shared__ uint8_t Abuf[32768];
  const int tid = threadIdx.x, wv = tid >> 6, lane = tid & 63;
  const int l15 = lane & 15, l4 = lane >> 4;
  const int col = wv * 16 + l15;
  const int b0 = blockIdx.x;

  // B fragments for this wave's 16 cols: 32 VGPR, loaded ONCE
  bf16x8 bfrag[8];
#pragma unroll
  for (int s = 0; s < 8; ++s)
    bfrag[s] = *reinterpret_cast<const bf16x8*>(Wbf + col * 256 + l4 * 8 + s * 32);

  uint32_t pk1[2][8];                        // packed L1 outputs [tile][rf*2+p]

#pragma unroll
  for (int t = 0; t < 2; ++t) {
    // ---- stage tile t: 2048 x 16B chunks via global_load_lds ----
#pragma unroll
    for (int k = 0; k < 4; ++k) {
      const int ct = tid + k * 512;          // linear LDS chunk [0,2048)
      const int arow = ct >> 5;
      const int c = (ct & 31) ^ (arow & 7);  // pre-swizzled logical chunk
      const void* src;
      if (LEAF) {
        const int seg = c >> 3;              // [posL|wrdL|posR|wrdR]
        const int leaf = 2 * (b0 * 128 + t * 64 + arow) + (seg >> 1);
        const int idx = (seg & 1) ? wrd_idx[leaf] : pos_idx[leaf];
        const uint16_t* tab = (seg & 1) ? wrd_bf : pos_bf;
        src = tab + (size_t)idx * 64 + (c & 7) * 8;
      } else {
        src = X + ((size_t)(b0 * 128 + t * 64 + arow)) * 256 + c * 8;
      }
      gl2lds16(src, &Abuf[ct << 4]);
    }
    __syncthreads();                         // staged

    // ---- GEMM1 tile t (64 rows x 16 cols per wave) ----
    f32x4 acc[4] = {};
    gemm16(Abuf, bfrag, l15, l4, acc);
#pragma unroll
    for (int rf = 0; rf < 4; ++rf) {
#pragma unroll
      for (int p = 0; p < 2; ++p) {
        const int r1 = t * 64 + rf * 16 + l4 * 4 + 2 * p;
        const int nia = nidx[off1 + b0 * 128 + r1];
        const int nib = nidx[off1 + b0 * 128 + r1 + 1];
        const float va = acc[rf][2 * p]     + wnp[nia * 128 + col];
        const float vb = acc[rf][2 * p + 1] + wnp[nib * 128 + col];
        pk1[t][rf * 2 + p] = (uint32_t)f2bf(ftanh(va)) | ((uint32_t)f2bf(ftanh(vb)) << 16);
      }
    }
    __syncthreads();                         // tile t LDS reads done; Abuf reusable
  }

  // ---- write Mid (= Abuf, next-level A layout, swizzled) from packed regs ----
#pragma unroll
  for (int t = 0; t < 2; ++t)
#pragma unroll
    for (int rf = 0; rf < 4; ++rf)
#pragma unroll
      for (int reg = 0; reg < 4; ++reg) {
        const int r1 = t * 64 + rf * 16 + l4 * 4 + reg;
        const int r2 = r1 >> 1;
        const int colA = (r1 & 1) * 128 + col;
        const uint16_t vv = (uint16_t)(pk1[t][rf * 2 + (reg >> 1)] >> ((reg & 1) * 16));
        *reinterpret_cast<uint16_t*>(
            &Abuf[r2 * 512 + (((colA >> 3) ^ (r2 & 7)) << 4) + (colA & 7) * 2]) = vv;
      }
  __syncthreads();                           // Mid complete

  // ---- GEMM2 from Mid; epilogue -> OutS (overlay Abuf after barrier) ----
  {
    f32x4 acc[4] = {};
    gemm16(Abuf, bfrag, l15, l4, acc);
    __syncthreads();                         // Mid reads done; OutS may overlay
#pragma unroll
    for (int rf = 0; rf < 4; ++rf)
#pragma unroll
      for (int reg = 0; reg < 4; ++reg) {
        const int row = rf * 16 + l4 * 4 + reg;
        const int ni = nidx[off2 + b0 * 64 + row];
        const float v = acc[rf][reg] + wnp[ni * 128 + col];
        const int colb = col * 2;
        *reinterpret_cast<uint16_t*>(
            &Abuf[row * 256 + (((colb >> 4) ^ (row & 7)) << 4) + (colb & 15)]) =
            f2bf(ftanh(v));
      }
  }
  __syncthreads();                           // OutS complete

  // ---- coalesced store: 512 threads x 32B contiguous ----
  {
    const int row = tid >> 3, c2 = (tid & 7) * 2;
    int4 v0 = *reinterpret_cast<const int4*>(&Abuf[row * 256 + ((c2       ^ (row & 7)) << 4)]);
    int4 v1 = *reinterpret_cast<const int4*>(&Abuf[row * 256 + (((c2 + 1) ^ (row & 7)) << 4)]);
    uint8_t* dst = reinterpret_cast<uint8_t*>(Y) + ((size_t)b0 * 64 + row) * 256 + c2 * 16;
    *reinterpret_cast<int4*>(dst) = v0;
    *reinterpret_cast<int4*>(dst + 16) = v1;
  }
}

// ---- small level: 1 wave / 16-row tile, no LDS, no barriers ----
__global__ __launch_bounds__(64, 4)
void small_kernel(const uint16_t* __restrict__ X, uint16_t* __restrict__ Y,
                  const uint16_t* __restrict__ Wbf, const float* __restrict__ wnp,
                  const int* __restrict__ nidx, int off)
{
  const int lane = threadIdx.x, l15 = lane & 15, l4 = lane >> 4;
  const int r0 = blockIdx.x * 16;
  f32x4 acc[8] = {};
  const uint16_t* Xr = X + (size_t)(r0 + l15) * 256 + l4 * 8;
#pragma unroll
  for (int s = 0; s < 8; ++s) {
    bf16x8 a = *reinterpret_cast<const bf16x8*>(Xr + s * 32);
#pragma unroll
    for (int cf = 0; cf < 8; ++cf) {
      bf16x8 b = *reinterpret_cast<const bf16x8*>(Wbf + (cf * 16 + l15) * 256 + l4 * 8 + s * 32);
      acc[cf] = MFMA(a, b, acc[cf], 0, 0, 0);
    }
  }
#pragma unroll
  for (int reg = 0; reg < 4; ++reg) {
    const int row = r0 + l4 * 4 + reg;
    const int ni = nidx[off + row];
#pragma unroll
    for (int cf = 0; cf < 8; ++cf) {
      const int c = cf * 16 + l15;
      const float v = acc[cf][reg] + wnp[ni * 128 + c];
      Y[(size_t)row * 128 + c] = f2bf(ftanh(v));
    }
  }
}

// ---- tail: levels n=256..1 in ONE block ----
__global__ __launch_bounds__(512, 1)
void tail_kernel(const uint16_t* __restrict__ X, const uint16_t* __restrict__ Wbf,
                 const float* __restrict__ wnp,
                 const int* __restrict__ nidx, int base_off, float* __restrict__ out)
{
  __shared__ uint8_t P[98304];   // buf0 @0 (64KB), buf1 @65536 (32KB)
  const int tid = threadIdx.x, w = tid >> 6, lane = tid & 63;
  const int Rw = (w >> 2) * 32, Cw = (w & 3) * 32;
  const int l15 = lane & 15, l4 = lane >> 4;

  bf16x8 bfrag[2][8];
#pragma unroll
  for (int cf = 0; cf < 2; ++cf) {
    const uint16_t* bp = Wbf + (Cw + cf * 16 + l15) * 256 + l4 * 8;
#pragma unroll
    for (int s = 0; s < 8; ++s)
      bfrag[cf][s] = *reinterpret_cast<const bf16x8*>(bp + s * 32);
  }

  int off = base_off;

  // ---- n=256 from global (512 input rows) ----
  for (int t = 0; t < 4; ++t) {
    f32x4 acc[2][2] = {};
    const uint16_t* Xa = X + (size_t)(t * 64 + Rw + l15) * 256 + l4 * 8;
    const uint16_t* Xb = Xa + 16 * 256;
#pragma unroll
    for (int s = 0; s < 8; ++s) {
      bf16x8 a0 = *reinterpret_cast<const bf16x8*>(Xa + s * 32);
      bf16x8 a1 = *reinterpret_cast<const bf16x8*>(Xb + s * 32);
      acc[0][0] = MFMA(a0, bfrag[0][s], acc[0][0], 0, 0, 0);
      acc[0][1] = MFMA(a0, bfrag[1][s], acc[0][1], 0, 0, 0);
      acc[1][0] = MFMA(a1, bfrag[0][s], acc[1][0], 0, 0, 0);
      acc[1][1] = MFMA(a1, bfrag[1][s], acc[1][1], 0, 0, 0);
    }
#pragma unroll
    for (int rf = 0; rf < 2; ++rf) {
#pragma unroll
      for (int reg = 0; reg < 4; ++reg) {
        const int r1 = t * 64 + Rw + rf * 16 + l4 * 4 + reg;
        const int ni = nidx[off + r1];
#pragma unroll
        for (int cf = 0; cf < 2; ++cf) {
          const int c = Cw + cf * 16 + l15;
          const float v = acc[rf][cf][reg] + wnp[ni * 128 + c];
          const int r2 = r1 >> 1;
          const int colA = (r1 & 1) * 128 + c;
          *reinterpret_cast<uint16_t*>(
              &P[r2 * 512 + (((colA >> 3) ^ (r2 & 7)) << 4) + (colA & 7) * 2]) =
              f2bf(ftanh(v));
        }
      }
    }
  }
  off += 256;
  __syncthreads();

  int cur = 0;
  for (int n = 128; n >= 1; n >>= 1) {
    const uint8_t* Pin = P + (cur ? 65536 : 0);
    uint8_t* Pout = P + (cur ? 0 : 65536);
    const int ntiles = (n + 63) >> 6;
    for (int t = 0; t < ntiles; ++t) {
      f32x4 acc[2][2] = {};
#pragma unroll
      for (int s = 0; s < 8; ++s) {
        bf16x8 a0 = *reinterpret_cast<const bf16x8*>(&Pin[lds_addr(t * 64 + Rw + l15,      s * 4 + l4)]);
        bf16x8 a1 = *reinterpret_cast<const bf16x8*>(&Pin[lds_addr(t * 64 + Rw + 16 + l15, s * 4 + l4)]);
        acc[0][0] = MFMA(a0, bfrag[0][s], acc[0][0], 0, 0, 0);
        acc[0][1] = MFMA(a0, bfrag[1][s], acc[0][1], 0, 0, 0);
        acc[1][0] = MFMA(a1, bfrag[0][s], acc[1][0], 0, 0, 0);
        acc[1][1] = MFMA(a1, bfrag[1][s], acc[1][1], 0, 0, 0);
      }
#pragma unroll
      for (int rf = 0; rf < 2; ++rf) {
#pragma unroll
        for (int reg = 0; reg < 4; ++reg) {
          const int rl = t * 64 + Rw + rf * 16 + l4 * 4 + reg;
          const int rcl = rl < n ? rl : n - 1;
          const int ni = nidx[off + rcl];
#pragma unroll
          for (int cf = 0; cf < 2; ++cf) {
            const int c = Cw + cf * 16 + l15;
            const float v = acc[rf][cf][reg] + wnp[ni * 128 + c];
            const float y = ftanh(v);
            if (n == 1) {
              if (rl == 0) out[c] = y;
            } else if (rl < n) {
              const int r2 = rl >> 1;
              const int colA = (rl & 1) * 128 + c;
              *reinterpret_cast<uint16_t*>(
                  &Pout[r2 * 512 + (((colA >> 3) ^ (r2 & 7)) << 4) + (colA & 7) * 2]) =
                  f2bf(y);
            }
          }
        }
      }
    }
    off += n;
    cur ^= 1;
    __syncthreads();
  }
}

// ---- prep: Wc_w/Wpos/Wwrd fp32->bf16; Wnon_pre = Wnon + bias (fp32) ----
// groups of 8 floats: Wc_w 4096, Wpos 512, Wwrd 800000, Wnon 1024. Total 805632.
__global__ void prep_all(const float* __restrict__ Wc_w, const float* __restrict__ Wpos,
                         const float* __restrict__ Wwrd, const float* __restrict__ Wnon,
                         const float* __restrict__ bias,
                         uint16_t* __restrict__ wc_bf, uint16_t* __restrict__ pos_bf,
                         uint16_t* __restrict__ wrd_bf, float* __restrict__ wnp)
{
  int g = blockIdx.x * 256 + threadIdx.x;
  if (g >= 804608) {                          // Wnon + bias -> fp32
    const int idx = g - 804608;               // [0,1024)
    float4 f0 = reinterpret_cast<const float4*>(Wnon)[idx * 2];
    float4 f1 = reinterpret_cast<const float4*>(Wnon)[idx * 2 + 1];
    const int cb = (idx * 8) & 127;
    f0.x += bias[cb];     f0.y += bias[cb + 1]; f0.z += bias[cb + 2]; f0.w += bias[cb + 3];
    f1.x += bias[cb + 4]; f1.y += bias[cb + 5]; f1.z += bias[cb + 6]; f1.w += bias[cb + 7];
    reinterpret_cast<float4*>(wnp)[idx * 2] = f0;
    reinterpret_cast<float4*>(wnp)[idx * 2 + 1] = f1;
    return;
  }
  const float* src; uint16_t* dst; int idx;
  if (g < 4096)      { src = Wc_w; dst = wc_bf;  idx = g; }
  else if (g < 4608) { src = Wpos; dst = pos_bf; idx = g - 4096; }
  else               { src = Wwrd; dst = wrd_bf; idx = g - 4608; }
  float4 f0 = reinterpret_cast<const float4*>(src)[idx * 2];
  float4 f1 = reinterpret_cast<const float4*>(src)[idx * 2 + 1];
  union { int4 v; uint16_t u[8]; } pkv;
  pkv.u[0] = f2bf(f0.x); pkv.u[1] = f2bf(f0.y); pkv.u[2] = f2bf(f0.z); pkv.u[3] = f2bf(f0.w);
  pkv.u[4] = f2bf(f1.x); pkv.u[5] = f2bf(f1.y); pkv.u[6] = f2bf(f1.z); pkv.u[7] = f2bf(f1.w);
  reinterpret_cast<int4*>(dst)[idx] = pkv.v;
}

extern "C" void kernel_launch(void* const* d_in, const int* in_sizes, int n_in,
                              void* d_out, int out_size, void* d_ws, size_t ws_size,
                              hipStream_t stream)
{
  const int*   pos_idx = (const int*)d_in[0];
  const int*   wrd_idx = (const int*)d_in[1];
  const int*   non_idx = (const int*)d_in[2];
  const float* Wwrd    = (const float*)d_in[3];
  const float* Wpos    = (const float*)d_in[4];
  const float* Wnon    = (const float*)d_in[5];
  const float* Wc_w    = (const float*)d_in[6];
  const float* Wc_b    = (const float*)d_in[7];
  float* out = (float*)d_out;

  uint8_t* ws = (uint8_t*)d_ws;
  uint16_t* Wbf    = (uint16_t*)ws;                               // 64 KiB
  uint16_t* pos_bf = (uint16_t*)(ws + 65536);                     // 8 KiB
  float*    wnp    = (float*)(ws + 73728);                        // 32 KiB
  uint16_t* wrd_bf = (uint16_t*)(ws + 106496);                    // 12.8 MB
  uint16_t* S1     = (uint16_t*)(ws + 12906496);                  // 33.6 MB
  uint16_t* S2     = (uint16_t*)(ws + 46460928);                  // 8.4 MB

  prep_all<<<3147, 256, 0, stream>>>(Wc_w, Wpos, Wwrd, Wnon, Wc_b,
                                     Wbf, pos_bf, wrd_bf, wnp);

  // Level offsets: L1=0(262144), L2=262144(131072), L3=393216(65536),
  // L4=458752(32768), L5=491520(16384), L6=507904(8192), L7=516096(4096),
  // L8=520192(2048), L9=522240(1024), L10=523264(512), tail from 523776.

  fused2_kernel<true><<<2048, 512, 0, stream>>>(nullptr, pos_idx, wrd_idx, pos_bf, wrd_bf,
                                                S1, Wbf, wnp, non_idx, 0, 262144);
  fused2_kernel<false><<<512, 512, 0, stream>>>(S1, nullptr, nullptr, nullptr, nullptr,
                                                S2, Wbf, wnp, non_idx, 393216, 458752);
  fused2_kernel<false><<<128, 512, 0, stream>>>(S2, nullptr, nullptr, nullptr, nullptr,
                                                S1, Wbf, wnp, non_idx, 491520, 507904);
  fused2_kernel<false><<<32, 512, 0, stream>>>(S1, nullptr, nullptr, nullptr, nullptr,
                                               S2, Wbf, wnp, non_idx, 516096, 520192);
  // L9 (n=1024): S2 (2048 rows) -> S1 ; L10 (n=512): S1 -> S2
  small_kernel<<<64, 64, 0, stream>>>(S2, S1, Wbf, wnp, non_idx, 522240);
  small_kernel<<<32, 64, 0, stream>>>(S1, S2, Wbf, wnp, non_idx, 523264);
  // tail: 256..1 (reads 512 rows in S2)
  tail_kernel<<<1, 512, 0, stream>>>(S2, Wbf, wnp, non_idx, 523776, out);
}

// Round 8
// 165.858 us; speedup vs baseline: 2.2456x; 1.1263x over previous
//
#include <hip/hip_runtime.h>
#include <stdint.h>

typedef __attribute__((ext_vector_type(8))) __bf16 bf16x8;
typedef __attribute__((ext_vector_type(4))) float f32x4;

#define MFMA __builtin_amdgcn_mfma_f32_16x16x32_bf16

// fp32 -> bf16 round-to-nearest-even
__device__ __forceinline__ uint16_t f2bf(float f) {
  uint32_t u = __float_as_uint(f);
  return (uint16_t)((u + 0x7fffu + ((u >> 16) & 1u)) >> 16);
}

// fast tanh: 1 - 2/(1+e^{2x}) with hw exp2+rcp. ~7 VALU ops.
// clamp makes it NaN/overflow-safe; rel err ~1e-6 << bf16 rounding.
__device__ __forceinline__ float ftanh(float v) {
  float x = fminf(fmaxf(v, -10.f), 10.f);
  float e = __builtin_amdgcn_exp2f(x * 2.885390081777927f);   // e^{2x}
  return 1.f - 2.f * __builtin_amdgcn_rcpf(e + 1.f);
}

// async 16B global->LDS (zero staging VGPRs)
__device__ __forceinline__ void gl2lds16(const void* g, void* l) {
  __builtin_amdgcn_global_load_lds(
      (const __attribute__((address_space(1))) unsigned int*)g,
      (__attribute__((address_space(3))) unsigned int*)l, 16, 0, 0);
}

// Swizzled LDS byte address for A-tiles: row-major [rows][256] bf16 (512 B/row),
// 16B chunks XORed by (row&7) (T2). Staging writes LINEAR; the XOR is applied
// to the per-lane global SOURCE address (involution on both sides).
__device__ __forceinline__ int lds_addr(int row, int chunk) {
  return row * 512 + ((chunk ^ (row & 7)) << 4);
}

// ---- 16-cols-per-wave GEMM: wave computes NRF*16 rows x 16 cols from LDS A ----
// bfrag = 8 frags (32 VGPR) stays register-resident (round-7 confirmed).
template<int NRF>
__device__ __forceinline__ void gemmN(const uint8_t* base, const bf16x8 bfrag[8],
                                      int l15, int l4, f32x4 acc[NRF]) {
#pragma unroll
  for (int s = 0; s < 8; ++s) {
#pragma unroll
    for (int rf = 0; rf < NRF; ++rf) {
      bf16x8 a = *reinterpret_cast<const bf16x8*>(&base[lds_addr(rf * 16 + l15, s * 4 + l4)]);
      acc[rf] = MFMA(a, bfrag[s], acc[rf], 0, 0, 0);
    }
  }
}

// ---- fused 3-level kernel, 48 KiB LDS ----
// Block b0: 256 inputs -> 128 L1 rows (2 tiles) -> 64 L2 rows -> 32 L3 rows.
// Regions: A/Mid1 = Abuf[0:32K) ; Mid2 = Abuf[32K:48K) ; OutS = Abuf[0:8K).
// Wave wv owns output cols [wv*16, wv*16+16) at every level.
template<bool LEAF>
__global__ __launch_bounds__(512, 4)
void fused3_kernel(const uint16_t* __restrict__ X,
                   const int* __restrict__ pos_idx, const int* __restrict__ wrd_idx,
                   const uint16_t* __restrict__ pos_bf, const uint16_t* __restrict__ wrd_bf,
                   uint16_t* __restrict__ Y, const uint16_t* __restrict__ Wbf,
                   const float* __restrict__ wnp,
                   const int* __restrict__ nidx, int off1, int off2, int off3)
{
  __shared__ uint8_t Abuf[49152];
  const int tid = threadIdx.x, wv = tid >> 6, lane = tid & 63;
  const int l15 = lane & 15, l4 = lane >> 4;
  const int col = wv * 16 + l15;
  const int b0 = blockIdx.x;

  // B fragments for this wave's 16 cols: 32 VGPR, loaded ONCE
  bf16x8 bfrag[8];
#pragma unroll
  for (int s = 0; s < 8; ++s)
    bfrag[s] = *reinterpret_cast<const bf16x8*>(Wbf + col * 256 + l4 * 8 + s * 32);

  uint32_t pk1[2][8];                        // packed L1 outputs [tile][rf*2+p]

  // ---- L1: two 64-row tiles through Abuf[0:32K) ----
#pragma unroll
  for (int t = 0; t < 2; ++t) {
#pragma unroll
    for (int k = 0; k < 4; ++k) {
      const int ct = tid + k * 512;          // linear LDS chunk [0,2048)
      const int arow = ct >> 5;
      const int c = (ct & 31) ^ (arow & 7);  // pre-swizzled logical chunk
      const void* src;
      if (LEAF) {
        const int seg = c >> 3;              // [posL|wrdL|posR|wrdR]
        const int leaf = 2 * (b0 * 128 + t * 64 + arow) + (seg >> 1);
        const int idx = (seg & 1) ? wrd_idx[leaf] : pos_idx[leaf];
        const uint16_t* tab = (seg & 1) ? wrd_bf : pos_bf;
        src = tab + (size_t)idx * 64 + (c & 7) * 8;
      } else {
        src = X + ((size_t)(b0 * 128 + t * 64 + arow)) * 256 + c * 8;
      }
      gl2lds16(src, &Abuf[ct << 4]);
    }
    __syncthreads();                         // staged

    f32x4 acc[4] = {};
    gemmN<4>(Abuf, bfrag, l15, l4, acc);
#pragma unroll
    for (int rf = 0; rf < 4; ++rf) {
#pragma unroll
      for (int p = 0; p < 2; ++p) {
        const int r1 = t * 64 + rf * 16 + l4 * 4 + 2 * p;
        const int nia = nidx[off1 + b0 * 128 + r1];
        const int nib = nidx[off1 + b0 * 128 + r1 + 1];
        const float va = acc[rf][2 * p]     + wnp[nia * 128 + col];
        const float vb = acc[rf][2 * p + 1] + wnp[nib * 128 + col];
        pk1[t][rf * 2 + p] = (uint32_t)f2bf(ftanh(va)) | ((uint32_t)f2bf(ftanh(vb)) << 16);
      }
    }
    __syncthreads();                         // tile t LDS reads done
  }

  // ---- Mid1 write (128 L1 rows -> 64 A-rows, overlays Abuf[0:32K)) ----
#pragma unroll
  for (int t = 0; t < 2; ++t)
#pragma unroll
    for (int rf = 0; rf < 4; ++rf)
#pragma unroll
      for (int reg = 0; reg < 4; ++reg) {
        const int r1 = t * 64 + rf * 16 + l4 * 4 + reg;
        const int r2 = r1 >> 1;
        const int colA = (r1 & 1) * 128 + col;
        const uint16_t vv = (uint16_t)(pk1[t][rf * 2 + (reg >> 1)] >> ((reg & 1) * 16));
        *reinterpret_cast<uint16_t*>(
            &Abuf[r2 * 512 + (((colA >> 3) ^ (r2 & 7)) << 4) + (colA & 7) * 2]) = vv;
      }
  __syncthreads();                           // Mid1 complete

  // ---- L2: gemm from Mid1; epilogue writes Mid2 DIRECTLY (disjoint region) ----
  {
    f32x4 acc[4] = {};
    gemmN<4>(Abuf, bfrag, l15, l4, acc);
    uint8_t* Mid2 = Abuf + 32768;
#pragma unroll
    for (int rf = 0; rf < 4; ++rf)
#pragma unroll
      for (int reg = 0; reg < 4; ++reg) {
        const int r2 = rf * 16 + l4 * 4 + reg;          // L2 row [0,64)
        const int ni = nidx[off2 + b0 * 64 + r2];
        const float v = acc[rf][reg] + wnp[ni * 128 + col];
        const int r3 = r2 >> 1;
        const int colA = (r2 & 1) * 128 + col;
        *reinterpret_cast<uint16_t*>(
            &Mid2[r3 * 512 + (((colA >> 3) ^ (r3 & 7)) << 4) + (colA & 7) * 2]) =
            f2bf(ftanh(v));
      }
  }
  __syncthreads();                           // Mid2 complete (+ Mid1 reads done)

  // ---- L3: gemm from Mid2 (32 rows); epilogue -> OutS = Abuf[0:8K) ----
  {
    f32x4 acc[2] = {};
    gemmN<2>(Abuf + 32768, bfrag, l15, l4, acc);
#pragma unroll
    for (int rf = 0; rf < 2; ++rf)
#pragma unroll
      for (int reg = 0; reg < 4; ++reg) {
        const int row = rf * 16 + l4 * 4 + reg;         // L3 row [0,32)
        const int ni = nidx[off3 + b0 * 32 + row];
        const float v = acc[rf][reg] + wnp[ni * 128 + col];
        const int colb = col * 2;
        *reinterpret_cast<uint16_t*>(
            &Abuf[row * 256 + (((colb >> 4) ^ (row & 7)) << 4) + (colb & 15)]) =
            f2bf(ftanh(v));
      }
  }
  __syncthreads();                           // OutS complete

  // ---- coalesced store: 512 threads x 16B (32 rows x 256B) ----
  {
    const int row = tid >> 4, c2 = tid & 15;
    int4 v = *reinterpret_cast<const int4*>(&Abuf[row * 256 + ((c2 ^ (row & 7)) << 4)]);
    *reinterpret_cast<int4*>(
        reinterpret_cast<uint8_t*>(Y) + ((size_t)b0 * 32 + row) * 256 + c2 * 16) = v;
  }
}

// ---- small level: 1 wave / 16-row tile, no LDS, no barriers ----
__global__ __launch_bounds__(64, 4)
void small_kernel(const uint16_t* __restrict__ X, uint16_t* __restrict__ Y,
                  const uint16_t* __restrict__ Wbf, const float* __restrict__ wnp,
                  const int* __restrict__ nidx, int off)
{
  const int lane = threadIdx.x, l15 = lane & 15, l4 = lane >> 4;
  const int r0 = blockIdx.x * 16;
  f32x4 acc[8] = {};
  const uint16_t* Xr = X + (size_t)(r0 + l15) * 256 + l4 * 8;
#pragma unroll
  for (int s = 0; s < 8; ++s) {
    bf16x8 a = *reinterpret_cast<const bf16x8*>(Xr + s * 32);
#pragma unroll
    for (int cf = 0; cf < 8; ++cf) {
      bf16x8 b = *reinterpret_cast<const bf16x8*>(Wbf + (cf * 16 + l15) * 256 + l4 * 8 + s * 32);
      acc[cf] = MFMA(a, b, acc[cf], 0, 0, 0);
    }
  }
#pragma unroll
  for (int reg = 0; reg < 4; ++reg) {
    const int row = r0 + l4 * 4 + reg;
    const int ni = nidx[off + row];
#pragma unroll
    for (int cf = 0; cf < 8; ++cf) {
      const int c = cf * 16 + l15;
      const float v = acc[cf][reg] + wnp[ni * 128 + c];
      Y[(size_t)row * 128 + c] = f2bf(ftanh(v));
    }
  }
}

// ---- tail: levels n=256..1 in ONE block, 16-cols-per-wave (B resident) ----
__global__ __launch_bounds__(512, 1)
void tail_kernel(const uint16_t* __restrict__ X, const uint16_t* __restrict__ Wbf,
                 const float* __restrict__ wnp,
                 const int* __restrict__ nidx, int base_off, float* __restrict__ out)
{
  __shared__ uint8_t P[98304];   // ping-pong: A @0 (<=64KB) / @65536 (<=32KB)
  const int tid = threadIdx.x, wv = tid >> 6, lane = tid & 63;
  const int l15 = lane & 15, l4 = lane >> 4;
  const int col = wv * 16 + l15;

  bf16x8 bfrag[8];
#pragma unroll
  for (int s = 0; s < 8; ++s)
    bfrag[s] = *reinterpret_cast<const bf16x8*>(Wbf + col * 256 + l4 * 8 + s * 32);

  int off = base_off;

  // ---- n=256: A (256 A-rows) from global; Mid (128 A-rows, 64KB) -> P[0] ----
  for (int t = 0; t < 4; ++t) {
    f32x4 acc[4] = {};
#pragma unroll
    for (int s = 0; s < 8; ++s)
#pragma unroll
      for (int rf = 0; rf < 4; ++rf) {
        bf16x8 a = *reinterpret_cast<const bf16x8*>(
            X + (size_t)(t * 64 + rf * 16 + l15) * 256 + s * 32 + l4 * 8);
        acc[rf] = MFMA(a, bfrag[s], acc[rf], 0, 0, 0);
      }
#pragma unroll
    for (int rf = 0; rf < 4; ++rf)
#pragma unroll
      for (int reg = 0; reg < 4; ++reg) {
        const int r1 = t * 64 + rf * 16 + l4 * 4 + reg;   // [0,256)
        const int ni = nidx[off + r1];
        const float v = acc[rf][reg] + wnp[ni * 128 + col];
        const int r2 = r1 >> 1;
        const int colA = (r1 & 1) * 128 + col;
        *reinterpret_cast<uint16_t*>(
            &P[r2 * 512 + (((colA >> 3) ^ (r2 & 7)) << 4) + (colA & 7) * 2]) =
            f2bf(ftanh(v));
      }
  }
  off += 256;
  __syncthreads();

  int cur = 0;                               // A for n=128 at P[0]
  for (int n = 128; n >= 1; n >>= 1) {
    const uint8_t* Pin = P + (cur ? 65536 : 0);
    uint8_t* Pout = P + (cur ? 0 : 65536);
    const int ntiles = (n + 63) >> 6;
    for (int t = 0; t < ntiles; ++t) {
      f32x4 acc[4] = {};
      gemmN<4>(Pin + t * 32768, bfrag, l15, l4, acc);
#pragma unroll
      for (int rf = 0; rf < 4; ++rf)
#pragma unroll
        for (int reg = 0; reg < 4; ++reg) {
          const int r1 = t * 64 + rf * 16 + l4 * 4 + reg;
          const int rcl = r1 < n ? r1 : n - 1;           // clamp for garbage rows
          const int ni = nidx[off + rcl];
          const float v = acc[rf][reg] + wnp[ni * 128 + col];
          const float y = ftanh(v);
          if (n == 1) {
            if (r1 == 0) out[col] = y;
          } else if (r1 < n) {
            const int r2 = r1 >> 1;
            const int colA = (r1 & 1) * 128 + col;
            *reinterpret_cast<uint16_t*>(
                &Pout[r2 * 512 + (((colA >> 3) ^ (r2 & 7)) << 4) + (colA & 7) * 2]) =
                f2bf(y);
          }
        }
    }
    off += n;
    cur ^= 1;
    __syncthreads();
  }
}

// ---- prep: Wc_w/Wpos/Wwrd fp32->bf16; wnp = Wnon + bias (fp32) ----
__global__ void prep_all(const float* __restrict__ Wc_w, const float* __restrict__ Wpos,
                         const float* __restrict__ Wwrd, const float* __restrict__ Wnon,
                         const float* __restrict__ bias,
                         uint16_t* __restrict__ wc_bf, uint16_t* __restrict__ pos_bf,
                         uint16_t* __restrict__ wrd_bf, float* __restrict__ wnp)
{
  int g = blockIdx.x * 256 + threadIdx.x;
  if (g >= 804608) {                          // Wnon + bias -> fp32
    const int idx = g - 804608;               // [0,1024)
    float4 f0 = reinterpret_cast<const float4*>(Wnon)[idx * 2];
    float4 f1 = reinterpret_cast<const float4*>(Wnon)[idx * 2 + 1];
    const int cb = (idx * 8) & 127;
    f0.x += bias[cb];     f0.y += bias[cb + 1]; f0.z += bias[cb + 2]; f0.w += bias[cb + 3];
    f1.x += bias[cb + 4]; f1.y += bias[cb + 5]; f1.z += bias[cb + 6]; f1.w += bias[cb + 7];
    reinterpret_cast<float4*>(wnp)[idx * 2] = f0;
    reinterpret_cast<float4*>(wnp)[idx * 2 + 1] = f1;
    return;
  }
  const float* src; uint16_t* dst; int idx;
  if (g < 4096)      { src = Wc_w; dst = wc_bf;  idx = g; }
  else if (g < 4608) { src = Wpos; dst = pos_bf; idx = g - 4096; }
  else               { src = Wwrd; dst = wrd_bf; idx = g - 4608; }
  float4 f0 = reinterpret_cast<const float4*>(src)[idx * 2];
  float4 f1 = reinterpret_cast<const float4*>(src)[idx * 2 + 1];
  union { int4 v; uint16_t u[8]; } pkv;
  pkv.u[0] = f2bf(f0.x); pkv.u[1] = f2bf(f0.y); pkv.u[2] = f2bf(f0.z); pkv.u[3] = f2bf(f0.w);
  pkv.u[4] = f2bf(f1.x); pkv.u[5] = f2bf(f1.y); pkv.u[6] = f2bf(f1.z); pkv.u[7] = f2bf(f1.w);
  reinterpret_cast<int4*>(dst)[idx] = pkv.v;
}

extern "C" void kernel_launch(void* const* d_in, const int* in_sizes, int n_in,
                              void* d_out, int out_size, void* d_ws, size_t ws_size,
                              hipStream_t stream)
{
  const int*   pos_idx = (const int*)d_in[0];
  const int*   wrd_idx = (const int*)d_in[1];
  const int*   non_idx = (const int*)d_in[2];
  const float* Wwrd    = (const float*)d_in[3];
  const float* Wpos    = (const float*)d_in[4];
  const float* Wnon    = (const float*)d_in[5];
  const float* Wc_w    = (const float*)d_in[6];
  const float* Wc_b    = (const float*)d_in[7];
  float* out = (float*)d_out;

  uint8_t* ws = (uint8_t*)d_ws;
  uint16_t* Wbf    = (uint16_t*)ws;                               // 64 KiB
  uint16_t* pos_bf = (uint16_t*)(ws + 65536);                     // 8 KiB
  float*    wnp    = (float*)(ws + 73728);                        // 32 KiB (Wnon+bias)
  uint16_t* wrd_bf = (uint16_t*)(ws + 106496);                    // 12.8 MB
  uint16_t* S1     = (uint16_t*)(ws + 12906496);                  // 16.8 MB (65536x128)
  uint16_t* S2     = (uint16_t*)(ws + 29683712);                  // 2.1 MB  (8192x128)
  uint16_t* S3     = (uint16_t*)(ws + 31780864);                  // 262 KB  (1024x128)
  uint16_t* S4     = (uint16_t*)(ws + 32043008);                  // 131 KB  (512x128)

  prep_all<<<3147, 256, 0, stream>>>(Wc_w, Wpos, Wwrd, Wnon, Wc_b,
                                     Wbf, pos_bf, wrd_bf, wnp);

  // Level offsets into non_idx: L1=0(262144), L2=262144(131072), L3=393216(65536),
  // L4=458752(32768), L5=491520(16384), L6=507904(8192), L7=516096(4096),
  // L8=520192(2048), L9=522240(1024), L10=523264(512), tail from 523776(256..1).

  // K1: gather -> L1,L2,L3 -> S1 (65536 rows)
  fused3_kernel<true><<<2048, 512, 0, stream>>>(nullptr, pos_idx, wrd_idx, pos_bf, wrd_bf,
                                                S1, Wbf, wnp, non_idx,
                                                0, 262144, 393216);
  // K2: S1 -> L4,L5,L6 -> S2 (8192 rows)
  fused3_kernel<false><<<256, 512, 0, stream>>>(S1, nullptr, nullptr, nullptr, nullptr,
                                                S2, Wbf, wnp, non_idx,
                                                458752, 491520, 507904);
  // K3: S2 -> L7,L8,L9 -> S3 (1024 rows)
  fused3_kernel<false><<<32, 512, 0, stream>>>(S2, nullptr, nullptr, nullptr, nullptr,
                                               S3, Wbf, wnp, non_idx,
                                               516096, 520192, 522240);
  // L10 (n=512): S3 -> S4
  small_kernel<<<32, 64, 0, stream>>>(S3, S4, Wbf, wnp, non_idx, 523264);
  // tail: 256..1 (reads 512 rows in S4)
  tail_kernel<<<1, 512, 0, stream>>>(S4, Wbf, wnp, non_idx, 523776, out);
}

// Round 9
// 165.103 us; speedup vs baseline: 2.2559x; 1.0046x over previous
//
#include <hip/hip_runtime.h>
#include <stdint.h>

typedef __attribute__((ext_vector_type(8))) __bf16 bf16x8;
typedef __attribute__((ext_vector_type(4))) float f32x4;

#define MFMA __builtin_amdgcn_mfma_f32_16x16x32_bf16

// fp32 -> bf16 round-to-nearest-even
__device__ __forceinline__ uint16_t f2bf(float f) {
  uint32_t u = __float_as_uint(f);
  return (uint16_t)((u + 0x7fffu + ((u >> 16) & 1u)) >> 16);
}

// fast tanh: 1 - 2/(1+e^{2x}) with hw exp2+rcp; clamp = NaN/overflow-safe
__device__ __forceinline__ float ftanh(float v) {
  float x = fminf(fmaxf(v, -10.f), 10.f);
  float e = __builtin_amdgcn_exp2f(x * 2.885390081777927f);
  return 1.f - 2.f * __builtin_amdgcn_rcpf(e + 1.f);
}

// pack two tanh'd floats into u32 (lo = even row, hi = odd row)
__device__ __forceinline__ uint32_t pk2f(float a, float b) {
  return (uint32_t)f2bf(ftanh(a)) | ((uint32_t)f2bf(ftanh(b)) << 16);
}

// async 16B global->LDS (zero staging VGPRs)
__device__ __forceinline__ void gl2lds16(const void* g, void* l) {
  __builtin_amdgcn_global_load_lds(
      (const __attribute__((address_space(1))) unsigned int*)g,
      (__attribute__((address_space(3))) unsigned int*)l, 16, 0, 0);
}

// A-tile LDS addr: row-major [rows][512B], 16B chunks XOR (row&7) (T2).
__device__ __forceinline__ int lds_addr(int row, int chunk) {
  return row * 512 + ((chunk ^ (row & 7)) << 4);
}
// interleaved u32 write addr for k'-pair (2col, 2col+1) in A-row r2
__device__ __forceinline__ int ildw_addr(int r2, int col) {
  return r2 * 512 + (((col >> 2) ^ (r2 & 7)) << 4) + ((col & 3) << 2);
}
// one-hot region: [rows][128B], 8 chunks/row, same XOR swizzle
__device__ __forceinline__ int oh_addr(int row, int chunk) {
  return row * 128 + ((chunk ^ (row & 7)) << 4);
}

// GEMM over NRF*16 A-rows x 16 cols: 8 s-steps from A (k=256) + 2 from one-hot (k=64)
template<int NRF>
__device__ __forceinline__ void gemmO(const uint8_t* Ab, const uint8_t* ohb,
                                      const bf16x8 bfrag[10], int l15, int l4,
                                      f32x4 acc[NRF]) {
#pragma unroll
  for (int s = 0; s < 8; ++s)
#pragma unroll
    for (int rf = 0; rf < NRF; ++rf) {
      bf16x8 a = *reinterpret_cast<const bf16x8*>(&Ab[lds_addr(rf * 16 + l15, s * 4 + l4)]);
      acc[rf] = MFMA(a, bfrag[s], acc[rf], 0, 0, 0);
    }
#pragma unroll
  for (int s = 0; s < 2; ++s)
#pragma unroll
    for (int rf = 0; rf < NRF; ++rf) {
      bf16x8 a = *reinterpret_cast<const bf16x8*>(&ohb[oh_addr(rf * 16 + l15, s * 4 + l4)]);
      acc[rf] = MFMA(a, bfrag[8 + s], acc[rf], 0, 0, 0);
    }
}

// stage one-hot rows: thread r zeroes its row (swizzled chunks) then sets bf16 1.0 at ni
__device__ __forceinline__ void stage_oh(uint8_t* oh, const int* __restrict__ nib,
                                         int rows, int tid) {
  if (tid < rows) {
    const int ni = nib[tid];
    const int4 z = {0, 0, 0, 0};
#pragma unroll
    for (int c = 0; c < 8; ++c)
      *reinterpret_cast<int4*>(&oh[oh_addr(tid, c)]) = z;
    *reinterpret_cast<uint16_t*>(&oh[oh_addr(tid, ni >> 3) + ((ni & 7) << 1)]) = 0x3F80;
  }
}

// ---- fused 3- or 4-level kernel, 48 KiB LDS ----
// Block: 128 A-rows in (2 tiles of 64) -> 128 -> 64 -> 32 (-> 16) output rows.
// Regions: A/Mid1 [0,32K); OH [32K,40K); Mid2 [0,16K); Mid3/OutS [16K,24K); OutS4 [0,4K).
// All state interleaved (k' = 2*col+side); leaf L1 uses natural-order WbfN, rest WbfI.
template<bool LEAF, bool FOUR>
__global__ __launch_bounds__(512, 4)
void fused_kernel(const uint16_t* __restrict__ X,
                  const int* __restrict__ pos_idx, const int* __restrict__ wrd_idx,
                  const uint16_t* __restrict__ pos_bf, const uint16_t* __restrict__ wrd_bf,
                  uint16_t* __restrict__ Y,
                  const uint16_t* __restrict__ WbfN, const uint16_t* __restrict__ WbfI,
                  const int* __restrict__ nidx, int off1, int off2, int off3, int off4)
{
  __shared__ uint8_t L[49152];
  uint8_t* OH = L + 32768;
  const int tid = threadIdx.x, wv = tid >> 6, lane = tid & 63;
  const int l15 = lane & 15, l4 = lane >> 4;
  const int col = wv * 16 + l15;
  const int b0 = blockIdx.x;

  bf16x8 bfrag[10];
  {
    const uint16_t* Wb = LEAF ? WbfN : WbfI;
#pragma unroll
    for (int s = 0; s < 10; ++s)
      bfrag[s] = *reinterpret_cast<const bf16x8*>(Wb + col * 320 + s * 32 + l4 * 8);
  }

  uint32_t pk1[2][8];

  // ---- L1: two 64-row tiles ----
#pragma unroll
  for (int t = 0; t < 2; ++t) {
#pragma unroll
    for (int k = 0; k < 4; ++k) {
      const int ct = tid + k * 512;          // linear LDS chunk [0,2048)
      const int arow = ct >> 5;
      const int c = (ct & 31) ^ (arow & 7);  // pre-swizzled logical chunk
      const void* src;
      if (LEAF) {
        const int seg = c >> 3;              // [posL|wrdL|posR|wrdR]
        const int leaf = 2 * (b0 * 128 + t * 64 + arow) + (seg >> 1);
        const int idx = (seg & 1) ? wrd_idx[leaf] : pos_idx[leaf];
        const uint16_t* tab = (seg & 1) ? wrd_bf : pos_bf;
        src = tab + (size_t)idx * 64 + (c & 7) * 8;
      } else {
        src = X + ((size_t)(b0 * 128 + t * 64 + arow)) * 256 + c * 8;
      }
      gl2lds16(src, &L[ct << 4]);
    }
    stage_oh(OH, nidx + off1 + b0 * 128 + t * 64, 64, tid);
    __syncthreads();                         // A + OH staged

    f32x4 acc[4] = {};
    gemmO<4>(L, OH, bfrag, l15, l4, acc);
#pragma unroll
    for (int rf = 0; rf < 4; ++rf)
#pragma unroll
      for (int p = 0; p < 2; ++p)
        pk1[t][rf * 2 + p] = pk2f(acc[rf][2 * p], acc[rf][2 * p + 1]);
    __syncthreads();                         // A + OH reads done
  }

  if (LEAF) {                                // switch B to interleaved for L2+
#pragma unroll
    for (int s = 0; s < 10; ++s)
      bfrag[s] = *reinterpret_cast<const bf16x8*>(WbfI + col * 320 + s * 32 + l4 * 8);
  }

  // ---- write Mid1 (interleaved u32) + stage oh(L2) ----
#pragma unroll
  for (int t = 0; t < 2; ++t)
#pragma unroll
    for (int rf = 0; rf < 4; ++rf)
#pragma unroll
      for (int p = 0; p < 2; ++p) {
        const int r2 = t * 32 + rf * 8 + l4 * 2 + p;
        *reinterpret_cast<uint32_t*>(&L[ildw_addr(r2, col)]) = pk1[t][rf * 2 + p];
      }
  stage_oh(OH, nidx + off2 + b0 * 64, 64, tid);
  __syncthreads();                           // Mid1 + OH ready

  // ---- L2 gemm -> pk2 regs ----
  uint32_t pk2[8];
  {
    f32x4 acc[4] = {};
    gemmO<4>(L, OH, bfrag, l15, l4, acc);
#pragma unroll
    for (int rf = 0; rf < 4; ++rf)
#pragma unroll
      for (int p = 0; p < 2; ++p)
        pk2[rf * 2 + p] = pk2f(acc[rf][2 * p], acc[rf][2 * p + 1]);
  }
  __syncthreads();                           // Mid1 + OH reads done

  // ---- write Mid2 [0,16K) + stage oh(L3) ----
#pragma unroll
  for (int rf = 0; rf < 4; ++rf)
#pragma unroll
    for (int p = 0; p < 2; ++p) {
      const int r3 = rf * 8 + l4 * 2 + p;
      *reinterpret_cast<uint32_t*>(&L[ildw_addr(r3, col)]) = pk2[rf * 2 + p];
    }
  stage_oh(OH, nidx + off3 + b0 * 32, 32, tid);
  __syncthreads();                           // Mid2 + OH ready

  // ---- L3 gemm from Mid2; write Mid3/OutS [16K,24K) directly ----
  {
    f32x4 acc[2] = {};
    gemmO<2>(L, OH, bfrag, l15, l4, acc);
#pragma unroll
    for (int rf = 0; rf < 2; ++rf)
#pragma unroll
      for (int p = 0; p < 2; ++p) {
        const int rY = rf * 8 + l4 * 2 + p;
        *reinterpret_cast<uint32_t*>(&L[16384 + ildw_addr(rY, col)]) =
            pk2f(acc[rf][2 * p], acc[rf][2 * p + 1]);
      }
  }
  __syncthreads();                           // Mid3/OutS complete

  if (FOUR) {
    stage_oh(OH, nidx + off4 + b0 * 16, 16, tid);
    __syncthreads();                         // OH(L4) ready
    f32x4 acc[1] = {};
    gemmO<1>(L + 16384, OH, bfrag, l15, l4, acc);
#pragma unroll
    for (int p = 0; p < 2; ++p) {
      const int rY = l4 * 2 + p;
      *reinterpret_cast<uint32_t*>(&L[ildw_addr(rY, col)]) =
          pk2f(acc[0][2 * p], acc[0][2 * p + 1]);
    }
    __syncthreads();
    if (tid < 256) {                         // 8 A-rows x 512B = 4K out
      const int i = tid >> 5, c = tid & 31;
      int4 v = *reinterpret_cast<const int4*>(&L[i * 512 + ((c ^ (i & 7)) << 4)]);
      *reinterpret_cast<int4*>(
          reinterpret_cast<uint8_t*>(Y) + ((size_t)b0 * 8 + i) * 512 + c * 16) = v;
    }
  } else {
    const int i = tid >> 5, c = tid & 31;    // 16 A-rows x 512B = 8K out
    int4 v = *reinterpret_cast<const int4*>(&L[16384 + i * 512 + ((c ^ (i & 7)) << 4)]);
    *reinterpret_cast<int4*>(
        reinterpret_cast<uint8_t*>(Y) + ((size_t)b0 * 16 + i) * 512 + c * 16) = v;
  }
}

// ---- tail: levels n=256..1 in ONE block (interleaved state, WbfI, fp32 wnp adds) ----
__global__ __launch_bounds__(512, 1)
void tail_kernel(const uint16_t* __restrict__ X, const uint16_t* __restrict__ WbfI,
                 const float* __restrict__ wnp, const int* __restrict__ nidx,
                 int base_off, float* __restrict__ out)
{
  __shared__ uint8_t P[98304];   // buf0 @0 (64K), buf1 @65536 (32K)
  const int tid = threadIdx.x, wv = tid >> 6, lane = tid & 63;
  const int l15 = lane & 15, l4 = lane >> 4;
  const int col = wv * 16 + l15;

  bf16x8 bfrag[8];
#pragma unroll
  for (int s = 0; s < 8; ++s)
    bfrag[s] = *reinterpret_cast<const bf16x8*>(WbfI + col * 320 + s * 32 + l4 * 8);

  int off = base_off;

  // n=256: 256 A-rows from global -> P0 (128 A-rows)
  for (int t = 0; t < 4; ++t) {
    f32x4 acc[4] = {};
#pragma unroll
    for (int s = 0; s < 8; ++s)
#pragma unroll
      for (int rf = 0; rf < 4; ++rf) {
        bf16x8 a = *reinterpret_cast<const bf16x8*>(
            X + (size_t)(t * 64 + rf * 16 + l15) * 256 + s * 32 + l4 * 8);
        acc[rf] = MFMA(a, bfrag[s], acc[rf], 0, 0, 0);
      }
#pragma unroll
    for (int rf = 0; rf < 4; ++rf)
#pragma unroll
      for (int reg = 0; reg < 4; ++reg) {
        const int r1 = t * 64 + rf * 16 + l4 * 4 + reg;
        const int ni = nidx[off + r1];
        const float v = acc[rf][reg] + wnp[ni * 128 + col];
        *reinterpret_cast<uint16_t*>(&P[ildw_addr(r1 >> 1, col) + (r1 & 1) * 2]) =
            f2bf(ftanh(v));
      }
  }
  off += 256;
  __syncthreads();

  int cur = 0;
  for (int n = 128; n >= 1; n >>= 1) {
    const uint8_t* Pin = P + (cur ? 65536 : 0);
    uint8_t* Pout = P + (cur ? 0 : 65536);
    const int ntiles = (n + 63) >> 6;
    for (int t = 0; t < ntiles; ++t) {
      f32x4 acc[4] = {};
#pragma unroll
      for (int s = 0; s < 8; ++s)
#pragma unroll
        for (int rf = 0; rf < 4; ++rf) {
          bf16x8 a = *reinterpret_cast<const bf16x8*>(
              &Pin[t * 32768 + lds_addr(rf * 16 + l15, s * 4 + l4)]);
          acc[rf] = MFMA(a, bfrag[s], acc[rf], 0, 0, 0);
        }
#pragma unroll
      for (int rf = 0; rf < 4; ++rf)
#pragma unroll
        for (int reg = 0; reg < 4; ++reg) {
          const int r1 = t * 64 + rf * 16 + l4 * 4 + reg;
          const int rcl = r1 < n ? r1 : n - 1;           // clamp for garbage rows
          const int ni = nidx[off + rcl];
          const float v = acc[rf][reg] + wnp[ni * 128 + col];
          const float y = ftanh(v);
          if (n == 1) {
            if (r1 == 0) out[col] = y;
          } else if (r1 < n) {
            *reinterpret_cast<uint16_t*>(&Pout[ildw_addr(r1 >> 1, col) + (r1 & 1) * 2]) =
                f2bf(y);
          }
        }
    }
    off += n;
    cur ^= 1;
    __syncthreads();
  }
}

// ---- prep: WbfN/WbfI (320-k, incl. Wnon+bias cols), pos/wrd bf16, wnp fp32 ----
__global__ void prep_all(const float* __restrict__ Wc_w, const float* __restrict__ Wpos,
                         const float* __restrict__ Wwrd, const float* __restrict__ Wnon,
                         const float* __restrict__ bias,
                         uint16_t* __restrict__ WbfN, uint16_t* __restrict__ WbfI,
                         uint16_t* __restrict__ pos_bf, uint16_t* __restrict__ wrd_bf,
                         float* __restrict__ wnp)
{
  int g = blockIdx.x * 256 + threadIdx.x;
  if (g < 10240) {                           // B matrices (scalar gather per elem)
    const bool INT = g >= 5120;
    const int gg = INT ? g - 5120 : g;
    uint16_t* dst = INT ? WbfI : WbfN;
    const int colc = gg / 40, kg = gg % 40;
    uint16_t u[8];
#pragma unroll
    for (int i = 0; i < 8; ++i) {
      const int kk = kg * 8 + i;
      float v;
      if (kk >= 256) v = Wnon[(kk - 256) * 128 + colc] + bias[colc];
      else {
        const int k = INT ? ((kk >> 1) + (kk & 1) * 128) : kk;
        v = Wc_w[colc * 256 + k];
      }
      u[i] = f2bf(v);
    }
    *reinterpret_cast<int4*>(dst + colc * 320 + kg * 8) = *reinterpret_cast<const int4*>(u);
    return;
  }
  int h = g - 10240;
  if (h < 800512) {                          // pos (512 groups) + wrd (800000 groups)
    const float* src; uint16_t* dst; int idx;
    if (h < 512) { src = Wpos; dst = pos_bf; idx = h; }
    else         { src = Wwrd; dst = wrd_bf; idx = h - 512; }
    float4 f0 = reinterpret_cast<const float4*>(src)[idx * 2];
    float4 f1 = reinterpret_cast<const float4*>(src)[idx * 2 + 1];
    union { int4 v; uint16_t u[8]; } pkv;
    pkv.u[0] = f2bf(f0.x); pkv.u[1] = f2bf(f0.y); pkv.u[2] = f2bf(f0.z); pkv.u[3] = f2bf(f0.w);
    pkv.u[4] = f2bf(f1.x); pkv.u[5] = f2bf(f1.y); pkv.u[6] = f2bf(f1.z); pkv.u[7] = f2bf(f1.w);
    reinterpret_cast<int4*>(dst)[idx] = pkv.v;
    return;
  }
  h -= 800512;
  if (h < 1024) {                            // wnp = Wnon + bias (fp32, for tail)
    float4 f0 = reinterpret_cast<const float4*>(Wnon)[h * 2];
    float4 f1 = reinterpret_cast<const float4*>(Wnon)[h * 2 + 1];
    const int cb = (h * 8) & 127;
    f0.x += bias[cb];     f0.y += bias[cb + 1]; f0.z += bias[cb + 2]; f0.w += bias[cb + 3];
    f1.x += bias[cb + 4]; f1.y += bias[cb + 5]; f1.z += bias[cb + 6]; f1.w += bias[cb + 7];
    reinterpret_cast<float4*>(wnp)[h * 2] = f0;
    reinterpret_cast<float4*>(wnp)[h * 2 + 1] = f1;
  }
}

extern "C" void kernel_launch(void* const* d_in, const int* in_sizes, int n_in,
                              void* d_out, int out_size, void* d_ws, size_t ws_size,
                              hipStream_t stream)
{
  const int*   pos_idx = (const int*)d_in[0];
  const int*   wrd_idx = (const int*)d_in[1];
  const int*   non_idx = (const int*)d_in[2];
  const float* Wwrd    = (const float*)d_in[3];
  const float* Wpos    = (const float*)d_in[4];
  const float* Wnon    = (const float*)d_in[5];
  const float* Wc_w    = (const float*)d_in[6];
  const float* Wc_b    = (const float*)d_in[7];
  float* out = (float*)d_out;

  uint8_t* ws = (uint8_t*)d_ws;
  uint16_t* WbfN   = (uint16_t*)ws;                    // 80 KiB (128x320)
  uint16_t* WbfI   = (uint16_t*)(ws + 81920);          // 80 KiB
  uint16_t* pos_bf = (uint16_t*)(ws + 163840);         // 8 KiB
  float*    wnp    = (float*)(ws + 172032);            // 32 KiB
  uint16_t* wrd_bf = (uint16_t*)(ws + 204800);         // 12.8 MB
  uint16_t* S1     = (uint16_t*)(ws + 13004800);       // 16.8 MB (32768 A-rows)
  uint16_t* S2     = (uint16_t*)(ws + 29782016);       // 2.1 MB  (4096 A-rows)
  uint16_t* S4     = (uint16_t*)(ws + 31879168);       // 128 KB  (256 A-rows)

  prep_all<<<3171, 256, 0, stream>>>(Wc_w, Wpos, Wwrd, Wnon, Wc_b,
                                     WbfN, WbfI, pos_bf, wrd_bf, wnp);

  // Level offsets: L1=0(262144), L2=262144(131072), L3=393216(65536),
  // L4=458752(32768), L5=491520(16384), L6=507904(8192), L7=516096(4096),
  // L8=520192(2048), L9=522240(1024), L10=523264(512), tail 523776(256..1).

  // K1: gather -> L1,L2,L3 -> S1
  fused_kernel<true, false><<<2048, 512, 0, stream>>>(
      nullptr, pos_idx, wrd_idx, pos_bf, wrd_bf, S1, WbfN, WbfI, non_idx,
      0, 262144, 393216, 0);
  // K2: S1 -> L4,L5,L6 -> S2
  fused_kernel<false, false><<<256, 512, 0, stream>>>(
      S1, nullptr, nullptr, nullptr, nullptr, S2, WbfN, WbfI, non_idx,
      458752, 491520, 507904, 0);
  // K3: S2 -> L7,L8,L9,L10 -> S4
  fused_kernel<false, true><<<32, 512, 0, stream>>>(
      S2, nullptr, nullptr, nullptr, nullptr, S4, WbfN, WbfI, non_idx,
      516096, 520192, 522240, 523264);
  // tail: 256..1 (reads 256 A-rows in S4)
  tail_kernel<<<1, 512, 0, stream>>>(S4, WbfI, wnp, non_idx, 523776, out);
}